// Round 4
// baseline (330.804 us; speedup 1.0000x reference)
//
#include <hip/hip_runtime.h>
#include <hip/hip_bf16.h>
#include <hip/hip_cooperative_groups.h>
#include <cstdint>
#include <cstddef>

namespace cg = cooperative_groups;

#define IC 512     // in_caps
#define IDM 768    // in_dim
#define KC 16      // num_caps
#define NB 128     // batch
#define NOUT 1024  // KC*DC

typedef __attribute__((ext_vector_type(8))) short short8v;
typedef __attribute__((ext_vector_type(4))) float f32x4;

#define MFMA __builtin_amdgcn_mfma_f32_16x16x32_bf16

static __device__ __forceinline__ ushort bf_hi(float x) {
  __hip_bfloat16 h = __float2bfloat16(x);
  return *reinterpret_cast<ushort*>(&h);
}
static __device__ __forceinline__ float bf_f(ushort u) {
  union { float f; unsigned u32; } z; z.u32 = ((unsigned)u) << 16; return z.f;
}
static __device__ __forceinline__ void split2(float x, ushort& h, ushort& l) {
  h = bf_hi(x); l = bf_hi(x - bf_f(h));
}

struct KArgs {
  const float *m, *q, *Ww, *Wb;
  ushort *Ah, *Al, *Bh, *Bl;          // bf16 hi/lo inputs for GEMM
  ushort *Hh, *Hl, *HTh, *HTl;        // hat_m [i][n] and [n][i]
  float *Yf; ushort *Yh, *Yl;         // running y (tmp_q)
  float *Vf; ushort *Vh, *Vl;         // running vsum
  ushort *Dh, *Dl;                    // dsp [b][k*512+i]
  float *summ, *invx, *sy, *invy;     // pearson row stats
  float *outp;
};

// ---- corr + softmax fused (block = 16i x 16b, waves split k) ----
template <int R>   // 0: round 0 (no a-dot, uniform d); 1: rounds 1,2
static __device__ __forceinline__ void corr_sm(
    const KArgs& A, int bid, int t,
    float (*p_lds)[256], float (*a_lds)[256])
{
  const int w = t >> 6, L = t & 63, c = L & 15, g = L >> 4;
  const int it = bid >> 3, bt = bid & 7;
  const int i0 = it * 16, b0 = bt * 16;

  #pragma unroll
  for (int kk4 = 0; kk4 < 4; ++kk4) {
    const int k = kk4 * 4 + w;
    const size_t koff = (size_t)k * 64 + g * 8;
    const ushort* pAh = A.Hh + (size_t)(i0 + c) * NOUT + koff;
    const ushort* pAl = A.Hl + (size_t)(i0 + c) * NOUT + koff;
    const ushort* pYh = A.Yh + (size_t)(b0 + c) * NOUT + koff;
    const ushort* pYl = A.Yl + (size_t)(b0 + c) * NOUT + koff;
    const ushort* pVh = A.Vh + (size_t)(b0 + c) * NOUT + koff;
    const ushort* pVl = A.Vl + (size_t)(b0 + c) * NOUT + koff;

    f32x4 P = {}, Aa = {};
    #pragma unroll
    for (int ks = 0; ks < 64; ks += 32) {
      const short8v ah = *(const short8v*)(pAh + ks);
      const short8v al = *(const short8v*)(pAl + ks);
      const short8v yh = *(const short8v*)(pYh + ks);
      const short8v yl = *(const short8v*)(pYl + ks);
      P = MFMA(ah, yh, P, 0, 0, 0);
      P = MFMA(ah, yl, P, 0, 0, 0);
      P = MFMA(al, yh, P, 0, 0, 0);
      if (R) {
        const short8v vh = *(const short8v*)(pVh + ks);
        const short8v vl = *(const short8v*)(pVl + ks);
        Aa = MFMA(ah, vh, Aa, 0, 0, 0);
        Aa = MFMA(ah, vl, Aa, 0, 0, 0);
        Aa = MFMA(al, vh, Aa, 0, 0, 0);
      }
    }
    const float syb = A.sy[(b0 + c) * KC + k];
    const float iyb = A.invy[(b0 + c) * KC + k];
    f32x4 pv;
    #pragma unroll
    for (int j = 0; j < 4; ++j) {
      const int i = i0 + 4 * g + j;
      pv[j] = tanhf((P[j] - A.summ[i * KC + k] * syb * (1.0f / 64.0f))
                    * A.invx[i * KC + k] * iyb);
    }
    *(f32x4*)&p_lds[k][c * 16 + 4 * g] = pv;
    if (R) *(f32x4*)&a_lds[k][c * 16 + 4 * g] = Aa;
  }
  __syncthreads();

  // per-thread softmax over k (cell: b_local = t>>4, i_local = t&15)
  const int bl = t >> 4, il = t & 15;
  const size_t dbase = (size_t)(b0 + bl) * 8192 + (size_t)(i0 + il);
  if (R == 0) {
    #pragma unroll
    for (int k = 0; k < 16; ++k) {
      const float x = 0.0625f - p_lds[k][t];
      ushort h, l2; split2(x, h, l2);
      A.Dh[dbase + (size_t)k * 512] = h;
      A.Dl[dbase + (size_t)k * 512] = l2;
    }
  } else {
    float av[16];
    float mx = -1e30f;
    #pragma unroll
    for (int k = 0; k < 16; ++k) { av[k] = a_lds[k][t]; mx = fmaxf(mx, av[k]); }
    float s = 0.f;
    #pragma unroll
    for (int k = 0; k < 16; ++k) { av[k] = __expf(av[k] - mx); s += av[k]; }
    const float inv = 1.0f / s;
    #pragma unroll
    for (int k = 0; k < 16; ++k) {
      const float x = av[k] * inv - p_lds[k][t];
      ushort h, l2; split2(x, h, l2);
      A.Dh[dbase + (size_t)k * 512] = h;
      A.Dl[dbase + (size_t)k * 512] = l2;
    }
  }
  __syncthreads();
}

// ---- hat_v via MFMA + squash + y/vsum update (block = (k, 16 b)) ----
template <int R>   // 0: vsum=v; 1: vsum+=v; 2: final (write outp only)
static __device__ __forceinline__ void hatv(
    const KArgs& A, int bid, int t,
    float (*red)[4][16], float* sscale)
{
  if (bid >= 128) return;
  const int w = t >> 6, L = t & 63, c = L & 15, g = L >> 4;
  const int k = bid & 15;
  const int b0 = (bid >> 4) * 16;

  const ushort* pAh = A.Dh + (size_t)(b0 + c) * 8192 + (size_t)k * 512 + g * 8;
  const ushort* pAl = A.Dl + (size_t)(b0 + c) * 8192 + (size_t)k * 512 + g * 8;
  const ushort* pBh = A.HTh + (size_t)(k * 64 + w * 16 + c) * 512 + g * 8;
  const ushort* pBl = A.HTl + (size_t)(k * 64 + w * 16 + c) * 512 + g * 8;

  f32x4 acc = {};
  #pragma unroll 4
  for (int i = 0; i < 512; i += 32) {
    const short8v ah = *(const short8v*)(pAh + i);
    const short8v al = *(const short8v*)(pAl + i);
    const short8v bh = *(const short8v*)(pBh + i);
    const short8v bl = *(const short8v*)(pBl + i);
    acc = MFMA(ah, bh, acc, 0, 0, 0);
    acc = MFMA(ah, bl, acc, 0, 0, 0);
    acc = MFMA(al, bh, acc, 0, 0, 0);
  }

  float sq[4];
  #pragma unroll
  for (int j = 0; j < 4; ++j) {
    sq[j] = acc[j] * acc[j];
    #pragma unroll
    for (int off = 1; off < 16; off <<= 1) sq[j] += __shfl_xor(sq[j], off);
  }
  if (c == 0) {
    #pragma unroll
    for (int j = 0; j < 4; ++j) red[0][w][4 * g + j] = sq[j];
  }
  __syncthreads();
  if (t < 16) {
    const float s = red[0][0][t] + red[0][1][t] + red[0][2][t] + red[0][3][t];
    sscale[t] = (s / (1.0f + s)) * rsqrtf(s + 1e-8f);
  }
  __syncthreads();

  const int d = w * 16 + c;
  float s1[4], s2[4];
  #pragma unroll
  for (int j = 0; j < 4; ++j) {
    const int bl_ = 4 * g + j;
    const int b = b0 + bl_;
    const float v = acc[j] * sscale[bl_];
    const size_t idx = (size_t)b * NOUT + (size_t)k * 64 + d;
    if (R == 2) {
      A.outp[idx] = v;
    } else {
      const float vs = (R == 0) ? v : (A.Vf[idx] + v);
      A.Vf[idx] = vs;
      ushort h, l2;
      split2(vs, h, l2); A.Vh[idx] = h; A.Vl[idx] = l2;
      const float yn = (A.Yf[idx] + v) * 0.5f;
      A.Yf[idx] = yn;
      split2(yn, h, l2); A.Yh[idx] = h; A.Yl[idx] = l2;
      s1[j] = yn; s2[j] = yn * yn;
    }
  }
  if (R != 2) {
    #pragma unroll
    for (int j = 0; j < 4; ++j) {
      #pragma unroll
      for (int off = 1; off < 16; off <<= 1) {
        s1[j] += __shfl_xor(s1[j], off);
        s2[j] += __shfl_xor(s2[j], off);
      }
    }
    if (c == 0) {
      #pragma unroll
      for (int j = 0; j < 4; ++j) {
        red[1][w][4 * g + j] = s1[j];
        red[2][w][4 * g + j] = s2[j];
      }
    }
    __syncthreads();
    if (t < 16) {
      const float s = red[1][0][t] + red[1][1][t] + red[1][2][t] + red[1][3][t];
      const float q2 = red[2][0][t] + red[2][1][t] + red[2][2][t] + red[2][3][t];
      A.sy[(b0 + t) * KC + k] = s;
      A.invy[(b0 + t) * KC + k] = rsqrtf(q2 - s * s * (1.0f / 64.0f));
    }
  }
}

// ===================== the mega kernel =====================
__global__ __launch_bounds__(256) void k_mega(KArgs A)
{
  __shared__ float p_lds[16][256];
  __shared__ float a_lds[16][256];
  __shared__ float sred[2][2][32];
  __shared__ float red[3][4][16];
  __shared__ float sscale[16];

  cg::grid_group gg = cg::this_grid();
  const int t = threadIdx.x;
  const int bid = blockIdx.x;
  const int w = t >> 6, L = t & 63, c = L & 15, g = L >> 4;

  // ---- P0: convert m,q,Ww to bf16 hi/lo ----
  for (int u = bid * 256 + t; u < 319488; u += 65536) {
    const int NA4 = 122880;
    const float* src; ushort *dh, *dl;
    if (u < NA4) {
      const int e = u * 4;
      src = (e < IC * IDM) ? (A.m + e) : (A.q + (e - IC * IDM));
      dh = A.Ah + e; dl = A.Al + e;
    } else {
      const int e = (u - NA4) * 4;
      src = A.Ww + e; dh = A.Bh + e; dl = A.Bl + e;
    }
    const float4 x = *(const float4*)src;
    ushort4 hv, lv;
    split2(x.x, hv.x, lv.x);
    split2(x.y, hv.y, lv.y);
    split2(x.z, hv.z, lv.z);
    split2(x.w, hv.w, lv.w);
    *(ushort4*)dh = hv;
    *(ushort4*)dl = lv;
  }
  gg.sync();

  // ---- P1: GEMM [A;Q]@Ww^T + bias, epilogue: splits, transpose, row stats ----
  for (int tile = bid; tile < 320; tile += 256) {
    const int rt = tile >> 4, nt = tile & 15;
    const int r0 = rt * 32, n0 = nt * 64;
    const int wr = w >> 1, wc = w & 1;
    const int arow = r0 + wr * 16 + c;
    const int bcol = n0 + wc * 32 + c;

    const ushort* pAh = A.Ah + (size_t)arow * IDM + g * 8;
    const ushort* pAl = A.Al + (size_t)arow * IDM + g * 8;
    const ushort* pBh = A.Bh + (size_t)bcol * IDM + g * 8;
    const ushort* pBl = A.Bl + (size_t)bcol * IDM + g * 8;

    f32x4 acc0 = {}, acc1 = {};
    #pragma unroll 4
    for (int kb = 0; kb < IDM; kb += 32) {
      const short8v ah  = *(const short8v*)(pAh + kb);
      const short8v al  = *(const short8v*)(pAl + kb);
      const short8v bh0 = *(const short8v*)(pBh + kb);
      const short8v bh1 = *(const short8v*)(pBh + 16 * IDM + kb);
      const short8v bl0 = *(const short8v*)(pBl + kb);
      const short8v bl1 = *(const short8v*)(pBl + 16 * IDM + kb);
      acc0 = MFMA(ah, bh0, acc0, 0, 0, 0);
      acc1 = MFMA(ah, bh1, acc1, 0, 0, 0);
      acc0 = MFMA(ah, bl0, acc0, 0, 0, 0);
      acc0 = MFMA(al, bh0, acc0, 0, 0, 0);
      acc1 = MFMA(ah, bl1, acc1, 0, 0, 0);
      acc1 = MFMA(al, bh1, acc1, 0, 0, 0);
    }

    const float bias0 = A.Wb[bcol];
    const float bias1 = A.Wb[bcol + 16];
    float v0s[4], v1s[4];
    #pragma unroll
    for (int j = 0; j < 4; ++j) { v0s[j] = acc0[j] + bias0; v1s[j] = acc1[j] + bias1; }

    #pragma unroll
    for (int j = 0; j < 4; ++j) {
      float s = v0s[j] + v1s[j];
      float q2 = v0s[j] * v0s[j] + v1s[j] * v1s[j];
      #pragma unroll
      for (int off = 1; off < 16; off <<= 1) {
        s += __shfl_xor(s, off);
        q2 += __shfl_xor(q2, off);
      }
      if (c == 0) {
        sred[wc][0][wr * 16 + 4 * g + j] = s;
        sred[wc][1][wr * 16 + 4 * g + j] = q2;
      }
    }

    ushort h0[4], l0[4], h1[4], l1[4];
    #pragma unroll
    for (int j = 0; j < 4; ++j) { split2(v0s[j], h0[j], l0[j]); split2(v1s[j], h1[j], l1[j]); }

    const int rowb = r0 + wr * 16 + 4 * g;
    if (rowb < IC) {
      #pragma unroll
      for (int j = 0; j < 4; ++j) {
        const size_t r = (size_t)(rowb + j) * NOUT;
        A.Hh[r + bcol] = h0[j]; A.Hl[r + bcol] = l0[j];
        A.Hh[r + bcol + 16] = h1[j]; A.Hl[r + bcol + 16] = l1[j];
      }
      *(ushort4*)&A.HTh[(size_t)bcol * 512 + rowb] = make_ushort4(h0[0], h0[1], h0[2], h0[3]);
      *(ushort4*)&A.HTl[(size_t)bcol * 512 + rowb] = make_ushort4(l0[0], l0[1], l0[2], l0[3]);
      *(ushort4*)&A.HTh[(size_t)(bcol + 16) * 512 + rowb] = make_ushort4(h1[0], h1[1], h1[2], h1[3]);
      *(ushort4*)&A.HTl[(size_t)(bcol + 16) * 512 + rowb] = make_ushort4(l1[0], l1[1], l1[2], l1[3]);
    } else {
      #pragma unroll
      for (int j = 0; j < 4; ++j) {
        const size_t r = (size_t)(rowb + j - IC) * NOUT;
        A.Yf[r + bcol] = v0s[j]; A.Yf[r + bcol + 16] = v1s[j];
        A.Yh[r + bcol] = h0[j]; A.Yl[r + bcol] = l0[j];
        A.Yh[r + bcol + 16] = h1[j]; A.Yl[r + bcol + 16] = l1[j];
      }
    }
    __syncthreads();
    if (t < 32) {
      const int row = r0 + t;
      const float s = sred[0][0][t] + sred[1][0][t];
      const float q2 = sred[0][1][t] + sred[1][1][t];
      const float inv = rsqrtf(q2 - s * s * (1.0f / 64.0f));
      if (row < IC) {
        A.summ[row * KC + nt] = s;
        A.invx[row * KC + nt] = inv;
      } else {
        A.sy[(row - IC) * KC + nt] = s;
        A.invy[(row - IC) * KC + nt] = inv;
      }
    }
    __syncthreads();
  }
  gg.sync();

  // ---- rounds ----
  corr_sm<0>(A, bid, t, p_lds, a_lds); gg.sync();
  hatv<0>(A, bid, t, red, sscale);     gg.sync();
  corr_sm<1>(A, bid, t, p_lds, a_lds); gg.sync();
  hatv<1>(A, bid, t, red, sscale);     gg.sync();
  corr_sm<1>(A, bid, t, p_lds, a_lds); gg.sync();
  hatv<2>(A, bid, t, red, sscale);
}

// ===================== launch =====================
extern "C" void kernel_launch(void* const* d_in, const int* in_sizes, int n_in,
                              void* d_out, int out_size, void* d_ws, size_t ws_size,
                              hipStream_t stream) {
  char* w = (char*)d_ws;
  KArgs A;
  A.m  = (const float*)d_in[0];
  A.q  = (const float*)d_in[1];
  A.Ww = (const float*)d_in[2];
  A.Wb = (const float*)d_in[3];
  A.Ah   = (ushort*)(w + 0);          //  640* 768*2 =  983040
  A.Al   = (ushort*)(w + 983040);
  A.Bh   = (ushort*)(w + 1966080);    // 1024* 768*2 = 1572864
  A.Bl   = (ushort*)(w + 3538944);
  A.Hh   = (ushort*)(w + 5111808);    //  512*1024*2 = 1048576
  A.Hl   = (ushort*)(w + 6160384);
  A.HTh  = (ushort*)(w + 7208960);    // 1024* 512*2 = 1048576
  A.HTl  = (ushort*)(w + 8257536);
  A.Yf   = (float*)(w + 9306112);     //  128*1024*4 =  524288
  A.Yh   = (ushort*)(w + 9830400);    //  128*1024*2 =  262144
  A.Yl   = (ushort*)(w + 10092544);
  A.Vf   = (float*)(w + 10354688);    //  524288
  A.Vh   = (ushort*)(w + 10878976);   //  262144
  A.Vl   = (ushort*)(w + 11141120);
  A.Dh   = (ushort*)(w + 11403264);   //  128*8192*2 = 2097152
  A.Dl   = (ushort*)(w + 13500416);
  A.summ = (float*)(w + 15597568);    // 32768
  A.invx = (float*)(w + 15630336);    // 32768
  A.sy   = (float*)(w + 15663104);    // 8192
  A.invy = (float*)(w + 15671296);    // 8192
  A.outp = (float*)d_out;

  void* kargs[] = { (void*)&A };
  hipLaunchCooperativeKernel((const void*)k_mega, dim3(256), dim3(256),
                             kargs, 0, stream);
}

// Round 5
// 219.435 us; speedup vs baseline: 1.5075x; 1.5075x over previous
//
#include <hip/hip_runtime.h>
#include <hip/hip_bf16.h>
#include <cstdint>
#include <cstddef>

#define IC 512     // in_caps
#define IDM 768    // in_dim
#define KC 16      // num_caps
#define NB 128     // batch
#define NOUT 1024  // KC*DC

typedef __attribute__((ext_vector_type(8))) short short8v;
typedef __attribute__((ext_vector_type(4))) float f32x4;

#define MFMA __builtin_amdgcn_mfma_f32_16x16x32_bf16

static __device__ __forceinline__ unsigned fbits(float x) {
  union { float f; unsigned u; } z; z.f = x; return z.u;
}
static __device__ __forceinline__ float bf_f(ushort u) {
  union { float f; unsigned u32; } z; z.u32 = ((unsigned)u) << 16; return z.f;
}
// truncation-based hi/lo split (3 VALU ops); residual after hi+lo ~2^-16 rel
static __device__ __forceinline__ void split2(float x, ushort& h, ushort& l) {
  h = (ushort)(fbits(x) >> 16);
  const float r = x - bf_f(h);
  l = (ushort)(fbits(r) >> 16);
}
static __device__ __forceinline__ void split8(const float* p, short8v& h, short8v& l) {
  const float4 x0 = *(const float4*)p;
  const float4 x1 = *(const float4*)(p + 4);
  const float xs[8] = {x0.x, x0.y, x0.z, x0.w, x1.x, x1.y, x1.z, x1.w};
  #pragma unroll
  for (int j = 0; j < 8; ++j) {
    ushort hh, ll; split2(xs[j], hh, ll);
    h[j] = (short)hh; l[j] = (short)ll;
  }
}

struct KArgs {
  const float *m, *q, *Ww, *Wb;
  ushort *Hh, *Hl, *HTh, *HTl;        // hat_m [i][n] and [n][i], bf16 hi/lo
  float *Yf[3]; ushort *Yh[3], *Yl[3];  // y per round
  float *Vf[2]; ushort *Vh[2], *Vl[2];  // vsum per round
  ushort *Dh[3], *Dl[3];              // dsp per round [b][k*512+i]
  float *summ, *invx;                 // hat_m row stats
  float *sy[3], *invy[3];             // y row stats per round
  unsigned *flagG, *flagC, *flagH;    // 320 / 3*256 / 2*128
  float *outp;
};

// ---- dataflow sync primitives ----
static __device__ __forceinline__ void set_flag(unsigned* f) {
  // caller guarantees a __syncthreads() (vmcnt drain) already happened
  __builtin_amdgcn_fence(__ATOMIC_RELEASE, "agent");
  __hip_atomic_store(f, 1u, __ATOMIC_RELAXED, __HIP_MEMORY_SCOPE_AGENT);
}
static __device__ __forceinline__ void wait_flags(const unsigned* f, int n, int t) {
  if (t < 64) {
    for (;;) {
      bool ok = true;
      for (int j = t; j < n; j += 64)
        ok &= (__hip_atomic_load(f + j, __ATOMIC_RELAXED,
                                 __HIP_MEMORY_SCOPE_AGENT) == 1u);
      if (__ballot(ok) == ~0ull) break;
      __builtin_amdgcn_s_sleep(1);
    }
  }
  __syncthreads();
  __builtin_amdgcn_fence(__ATOMIC_ACQUIRE, "agent");
}

// ---- GEMM tile: 32 rows x 64 cols, f32 loads + in-register hi/lo split ----
static __device__ __forceinline__ void gemm_tile(
    const KArgs& A, int tile, int t, float (*sred)[2][32])
{
  const int w = t >> 6, L = t & 63, c = L & 15, g = L >> 4;
  const int wr = w >> 1, wc = w & 1;
  const int rt = tile >> 4, nt = tile & 15;
  const int r0 = rt * 32, n0 = nt * 64;
  const int arow = r0 + wr * 16 + c;
  const int bcol = n0 + wc * 32 + c;
  const float* asrc = (arow < IC) ? (A.m + (size_t)arow * IDM)
                                  : (A.q + (size_t)(arow - IC) * IDM);
  const float* b0src = A.Ww + (size_t)bcol * IDM;
  const float* b1src = A.Ww + (size_t)(bcol + 16) * IDM;

  f32x4 acc0 = {}, acc1 = {};
  #pragma unroll 2
  for (int kb = 0; kb < IDM; kb += 32) {
    short8v ah, al, bh0, bl0, bh1, bl1;
    split8(asrc + kb + g * 8, ah, al);
    split8(b0src + kb + g * 8, bh0, bl0);
    split8(b1src + kb + g * 8, bh1, bl1);
    acc0 = MFMA(ah, bh0, acc0, 0, 0, 0);
    acc0 = MFMA(ah, bl0, acc0, 0, 0, 0);
    acc0 = MFMA(al, bh0, acc0, 0, 0, 0);
    acc1 = MFMA(ah, bh1, acc1, 0, 0, 0);
    acc1 = MFMA(ah, bl1, acc1, 0, 0, 0);
    acc1 = MFMA(al, bh1, acc1, 0, 0, 0);
  }

  const float bias0 = A.Wb[bcol];
  const float bias1 = A.Wb[bcol + 16];
  float v0s[4], v1s[4];
  #pragma unroll
  for (int j = 0; j < 4; ++j) { v0s[j] = acc0[j] + bias0; v1s[j] = acc1[j] + bias1; }

  #pragma unroll
  for (int j = 0; j < 4; ++j) {
    float s = v0s[j] + v1s[j];
    float q2 = v0s[j] * v0s[j] + v1s[j] * v1s[j];
    #pragma unroll
    for (int off = 1; off < 16; off <<= 1) {
      s += __shfl_xor(s, off);
      q2 += __shfl_xor(q2, off);
    }
    if (c == 0) {
      sred[wc][0][wr * 16 + 4 * g + j] = s;
      sred[wc][1][wr * 16 + 4 * g + j] = q2;
    }
  }

  ushort h0[4], l0[4], h1[4], l1[4];
  #pragma unroll
  for (int j = 0; j < 4; ++j) { split2(v0s[j], h0[j], l0[j]); split2(v1s[j], h1[j], l1[j]); }

  const int rowb = r0 + wr * 16 + 4 * g;
  if (rowb < IC) {
    #pragma unroll
    for (int j = 0; j < 4; ++j) {
      const size_t r = (size_t)(rowb + j) * NOUT;
      A.Hh[r + bcol] = h0[j]; A.Hl[r + bcol] = l0[j];
      A.Hh[r + bcol + 16] = h1[j]; A.Hl[r + bcol + 16] = l1[j];
    }
    *(ushort4*)&A.HTh[(size_t)bcol * 512 + rowb] = make_ushort4(h0[0], h0[1], h0[2], h0[3]);
    *(ushort4*)&A.HTl[(size_t)bcol * 512 + rowb] = make_ushort4(l0[0], l0[1], l0[2], l0[3]);
    *(ushort4*)&A.HTh[(size_t)(bcol + 16) * 512 + rowb] = make_ushort4(h1[0], h1[1], h1[2], h1[3]);
    *(ushort4*)&A.HTl[(size_t)(bcol + 16) * 512 + rowb] = make_ushort4(l1[0], l1[1], l1[2], l1[3]);
  } else {
    #pragma unroll
    for (int j = 0; j < 4; ++j) {
      const size_t r = (size_t)(rowb + j - IC) * NOUT;
      A.Yf[0][r + bcol] = v0s[j]; A.Yf[0][r + bcol + 16] = v1s[j];
      A.Yh[0][r + bcol] = h0[j]; A.Yl[0][r + bcol] = l0[j];
      A.Yh[0][r + bcol + 16] = h1[j]; A.Yl[0][r + bcol + 16] = l1[j];
    }
  }
  __syncthreads();
  if (t < 32) {
    const int row = r0 + t;
    const float s = sred[0][0][t] + sred[1][0][t];
    const float q2 = sred[0][1][t] + sred[1][1][t];
    const float inv = rsqrtf(q2 - s * s * (1.0f / 64.0f));
    if (row < IC) {
      A.summ[row * KC + nt] = s;
      A.invx[row * KC + nt] = inv;
    } else {
      A.sy[0][(row - IC) * KC + nt] = s;
      A.invy[0][(row - IC) * KC + nt] = inv;
    }
  }
  __syncthreads();
}

// ---- corr + softmax fused (block = 16i x 16b, waves split k) ----
template <int R>   // 0: round 0 (uniform d, no a-dot); 1: rounds 1,2
static __device__ __forceinline__ void corr_sm(
    const KArgs& A, int bid, int t,
    const ushort* Yh, const ushort* Yl,
    const ushort* Vh, const ushort* Vl,
    const float* sy, const float* invy,
    ushort* Dh, ushort* Dl,
    float (*p_lds)[256], float (*a_lds)[256])
{
  const int w = t >> 6, L = t & 63, c = L & 15, g = L >> 4;
  const int it = bid >> 3, bt = bid & 7;
  const int i0 = it * 16, b0 = bt * 16;

  #pragma unroll
  for (int kk4 = 0; kk4 < 4; ++kk4) {
    const int k = kk4 * 4 + w;
    const size_t koff = (size_t)k * 64 + g * 8;
    const ushort* pAh = A.Hh + (size_t)(i0 + c) * NOUT + koff;
    const ushort* pAl = A.Hl + (size_t)(i0 + c) * NOUT + koff;
    const ushort* pYh = Yh + (size_t)(b0 + c) * NOUT + koff;
    const ushort* pYl = Yl + (size_t)(b0 + c) * NOUT + koff;
    const ushort* pVh = Vh + (size_t)(b0 + c) * NOUT + koff;
    const ushort* pVl = Vl + (size_t)(b0 + c) * NOUT + koff;

    f32x4 P = {}, Aa = {};
    #pragma unroll
    for (int ks = 0; ks < 64; ks += 32) {
      const short8v ah = *(const short8v*)(pAh + ks);
      const short8v al = *(const short8v*)(pAl + ks);
      const short8v yh = *(const short8v*)(pYh + ks);
      const short8v yl = *(const short8v*)(pYl + ks);
      P = MFMA(ah, yh, P, 0, 0, 0);
      P = MFMA(ah, yl, P, 0, 0, 0);
      P = MFMA(al, yh, P, 0, 0, 0);
      if (R) {
        const short8v vh = *(const short8v*)(pVh + ks);
        const short8v vl = *(const short8v*)(pVl + ks);
        Aa = MFMA(ah, vh, Aa, 0, 0, 0);
        Aa = MFMA(ah, vl, Aa, 0, 0, 0);
        Aa = MFMA(al, vh, Aa, 0, 0, 0);
      }
    }
    const float syb = sy[(b0 + c) * KC + k];
    const float iyb = invy[(b0 + c) * KC + k];
    f32x4 pv;
    #pragma unroll
    for (int j = 0; j < 4; ++j) {
      const int i = i0 + 4 * g + j;
      pv[j] = tanhf((P[j] - A.summ[i * KC + k] * syb * (1.0f / 64.0f))
                    * A.invx[i * KC + k] * iyb);
    }
    *(f32x4*)&p_lds[k][c * 16 + 4 * g] = pv;
    if (R) *(f32x4*)&a_lds[k][c * 16 + 4 * g] = Aa;
  }
  __syncthreads();

  // softmax over k per (b_local = t>>4, i_local = t&15), dsp -> bf16 hi/lo
  const int bl = t >> 4, il = t & 15;
  const size_t dbase = (size_t)(b0 + bl) * 8192 + (size_t)(i0 + il);
  if (R == 0) {
    #pragma unroll
    for (int k = 0; k < 16; ++k) {
      const float x = 0.0625f - p_lds[k][t];
      ushort h, l2; split2(x, h, l2);
      Dh[dbase + (size_t)k * 512] = h;
      Dl[dbase + (size_t)k * 512] = l2;
    }
  } else {
    float av[16];
    float mx = -1e30f;
    #pragma unroll
    for (int k = 0; k < 16; ++k) { av[k] = a_lds[k][t]; mx = fmaxf(mx, av[k]); }
    float s = 0.f;
    #pragma unroll
    for (int k = 0; k < 16; ++k) { av[k] = __expf(av[k] - mx); s += av[k]; }
    const float inv = 1.0f / s;
    #pragma unroll
    for (int k = 0; k < 16; ++k) {
      const float x = av[k] * inv - p_lds[k][t];
      ushort h, l2; split2(x, h, l2);
      Dh[dbase + (size_t)k * 512] = h;
      Dl[dbase + (size_t)k * 512] = l2;
    }
  }
  __syncthreads();
}

// ---- hat_v via MFMA + squash + y/vsum update (block = (k, 16 b)) ----
template <int R>   // 0: vsum=v; 1: vsum+=v; 2: final (outp only)
static __device__ __forceinline__ void hatv_body(
    const KArgs& A, int bid, int t,
    const ushort* Dh, const ushort* Dl,
    const float* Yfin, float* Yfout, ushort* Yhout, ushort* Ylout,
    const float* Vfin, float* Vfout, ushort* Vhout, ushort* Vlout,
    float* syout, float* invyout,
    float (*red)[4][16], float* sscale)
{
  const int w = t >> 6, L = t & 63, c = L & 15, g = L >> 4;
  const int k = bid & 15;
  const int b0 = (bid >> 4) * 16;

  const ushort* pAh = Dh + (size_t)(b0 + c) * 8192 + (size_t)k * 512 + g * 8;
  const ushort* pAl = Dl + (size_t)(b0 + c) * 8192 + (size_t)k * 512 + g * 8;
  const ushort* pBh = A.HTh + (size_t)(k * 64 + w * 16 + c) * 512 + g * 8;
  const ushort* pBl = A.HTl + (size_t)(k * 64 + w * 16 + c) * 512 + g * 8;

  f32x4 acc = {};
  #pragma unroll 4
  for (int i = 0; i < 512; i += 32) {
    const short8v ah = *(const short8v*)(pAh + i);
    const short8v al = *(const short8v*)(pAl + i);
    const short8v bh = *(const short8v*)(pBh + i);
    const short8v bl = *(const short8v*)(pBl + i);
    acc = MFMA(ah, bh, acc, 0, 0, 0);
    acc = MFMA(ah, bl, acc, 0, 0, 0);
    acc = MFMA(al, bh, acc, 0, 0, 0);
  }

  float sq[4];
  #pragma unroll
  for (int j = 0; j < 4; ++j) {
    sq[j] = acc[j] * acc[j];
    #pragma unroll
    for (int off = 1; off < 16; off <<= 1) sq[j] += __shfl_xor(sq[j], off);
  }
  if (c == 0) {
    #pragma unroll
    for (int j = 0; j < 4; ++j) red[0][w][4 * g + j] = sq[j];
  }
  __syncthreads();
  if (t < 16) {
    const float s = red[0][0][t] + red[0][1][t] + red[0][2][t] + red[0][3][t];
    sscale[t] = (s / (1.0f + s)) * rsqrtf(s + 1e-8f);
  }
  __syncthreads();

  const int d = w * 16 + c;
  float s1[4], s2[4];
  #pragma unroll
  for (int j = 0; j < 4; ++j) {
    const int bl_ = 4 * g + j;
    const int b = b0 + bl_;
    const float v = acc[j] * sscale[bl_];
    const size_t idx = (size_t)b * NOUT + (size_t)k * 64 + d;
    if (R == 2) {
      A.outp[idx] = v;
    } else {
      const float vs = (R == 0) ? v : (Vfin[idx] + v);
      Vfout[idx] = vs;
      ushort h, l2;
      split2(vs, h, l2); Vhout[idx] = h; Vlout[idx] = l2;
      const float yn = (Yfin[idx] + v) * 0.5f;
      Yfout[idx] = yn;
      split2(yn, h, l2); Yhout[idx] = h; Ylout[idx] = l2;
      s1[j] = yn; s2[j] = yn * yn;
    }
  }
  if (R != 2) {
    #pragma unroll
    for (int j = 0; j < 4; ++j) {
      #pragma unroll
      for (int off = 1; off < 16; off <<= 1) {
        s1[j] += __shfl_xor(s1[j], off);
        s2[j] += __shfl_xor(s2[j], off);
      }
    }
    if (c == 0) {
      #pragma unroll
      for (int j = 0; j < 4; ++j) {
        red[1][w][4 * g + j] = s1[j];
        red[2][w][4 * g + j] = s2[j];
      }
    }
    __syncthreads();
    if (t < 16) {
      const float s = red[1][0][t] + red[1][1][t] + red[1][2][t] + red[1][3][t];
      const float q2 = red[2][0][t] + red[2][1][t] + red[2][2][t] + red[2][3][t];
      syout[(b0 + t) * KC + k] = s;
      invyout[(b0 + t) * KC + k] = rsqrtf(q2 - s * s * (1.0f / 64.0f));
    }
    __syncthreads();
  }
}

// ===================== the mega kernel (flag dataflow, no grid barriers) ========
__global__ __launch_bounds__(256) void k_mega(KArgs A)
{
  __shared__ float p_lds[16][256];
  __shared__ float a_lds[16][256];
  __shared__ float sred[2][2][32];
  __shared__ float red[3][4][16];
  __shared__ float sscale[16];

  const int t = threadIdx.x;
  const int bid = blockIdx.x;
  const int it = bid >> 3, bt = bid & 7;

  // ---- GEMM phase: tile bid; hatv-idle high blocks take tiles 256..319 ----
  gemm_tile(A, bid, t, sred);
  if (t == 0) set_flag(&A.flagG[bid]);
  if (bid >= 192) {
    gemm_tile(A, 256 + (bid - 192), t, sred);
    if (t == 0) set_flag(&A.flagG[256 + (bid - 192)]);
  }

  // ---- round 0: corr+softmax ----
  wait_flags(A.flagG + (it >> 1) * 16, 16, t);            // H rows + their stats
  wait_flags(A.flagG + (16 + (bt >> 1)) * 16, 16, t);     // y rows + stats
  corr_sm<0>(A, bid, t, A.Yh[0], A.Yl[0], A.Vh[0], A.Vl[0],
             A.sy[0], A.invy[0], A.Dh[0], A.Dl[0], p_lds, a_lds);
  if (t == 0) set_flag(&A.flagC[0 * 256 + bt * 32 + it]);

  if (bid < 128) {
    const int hbt = bid >> 4;
    wait_flags(A.flagG, 320, t);                          // full HT + Yf0
    wait_flags(A.flagC + 0 * 256 + hbt * 32, 32, t);
    hatv_body<0>(A, bid, t, A.Dh[0], A.Dl[0],
                 A.Yf[0], A.Yf[1], A.Yh[1], A.Yl[1],
                 nullptr, A.Vf[0], A.Vh[0], A.Vl[0],
                 A.sy[1], A.invy[1], red, sscale);
    if (t == 0) set_flag(&A.flagH[0 * 128 + bid]);
  }

  // ---- round 1 ----
  wait_flags(A.flagH + 0 * 128 + bt * 16, 16, t);
  corr_sm<1>(A, bid, t, A.Yh[1], A.Yl[1], A.Vh[0], A.Vl[0],
             A.sy[1], A.invy[1], A.Dh[1], A.Dl[1], p_lds, a_lds);
  if (t == 0) set_flag(&A.flagC[1 * 256 + bt * 32 + it]);

  if (bid < 128) {
    const int hbt = bid >> 4;
    wait_flags(A.flagC + 1 * 256 + hbt * 32, 32, t);
    hatv_body<1>(A, bid, t, A.Dh[1], A.Dl[1],
                 A.Yf[1], A.Yf[2], A.Yh[2], A.Yl[2],
                 A.Vf[0], A.Vf[1], A.Vh[1], A.Vl[1],
                 A.sy[2], A.invy[2], red, sscale);
    if (t == 0) set_flag(&A.flagH[1 * 128 + bid]);
  }

  // ---- round 2 (final) ----
  wait_flags(A.flagH + 1 * 128 + bt * 16, 16, t);
  corr_sm<1>(A, bid, t, A.Yh[2], A.Yl[2], A.Vh[1], A.Vl[1],
             A.sy[2], A.invy[2], A.Dh[2], A.Dl[2], p_lds, a_lds);
  if (t == 0) set_flag(&A.flagC[2 * 256 + bt * 32 + it]);

  if (bid < 128) {
    const int hbt = bid >> 4;
    wait_flags(A.flagC + 2 * 256 + hbt * 32, 32, t);
    hatv_body<2>(A, bid, t, A.Dh[2], A.Dl[2],
                 nullptr, nullptr, nullptr, nullptr,
                 nullptr, nullptr, nullptr, nullptr,
                 nullptr, nullptr, red, sscale);
  }
}

// ===================== launch =====================
extern "C" void kernel_launch(void* const* d_in, const int* in_sizes, int n_in,
                              void* d_out, int out_size, void* d_ws, size_t ws_size,
                              hipStream_t stream) {
  char* w = (char*)d_ws;
  KArgs A;
  A.m  = (const float*)d_in[0];
  A.q  = (const float*)d_in[1];
  A.Ww = (const float*)d_in[2];
  A.Wb = (const float*)d_in[3];
  A.Hh  = (ushort*)(w + 0);
  A.Hl  = (ushort*)(w + 1048576);
  A.HTh = (ushort*)(w + 2097152);
  A.HTl = (ushort*)(w + 3145728);
  A.Yf[0] = (float*)(w + 4194304);
  A.Yf[1] = (float*)(w + 4718592);
  A.Yf[2] = (float*)(w + 5242880);
  A.Yh[0] = (ushort*)(w + 5767168);
  A.Yh[1] = (ushort*)(w + 6029312);
  A.Yh[2] = (ushort*)(w + 6291456);
  A.Yl[0] = (ushort*)(w + 6553600);
  A.Yl[1] = (ushort*)(w + 6815744);
  A.Yl[2] = (ushort*)(w + 7077888);
  A.Vf[0] = (float*)(w + 7340032);
  A.Vf[1] = (float*)(w + 7864320);
  A.Vh[0] = (ushort*)(w + 8388608);
  A.Vh[1] = (ushort*)(w + 8650752);
  A.Vl[0] = (ushort*)(w + 8912896);
  A.Vl[1] = (ushort*)(w + 9175040);
  A.Dh[0] = (ushort*)(w + 9437184);
  A.Dh[1] = (ushort*)(w + 11534336);
  A.Dh[2] = (ushort*)(w + 13631488);
  A.Dl[0] = (ushort*)(w + 15728640);
  A.Dl[1] = (ushort*)(w + 17825792);
  A.Dl[2] = (ushort*)(w + 19922944);
  A.summ = (float*)(w + 22020096);
  A.invx = (float*)(w + 22052864);
  A.sy[0]   = (float*)(w + 22085632);
  A.sy[1]   = (float*)(w + 22093824);
  A.sy[2]   = (float*)(w + 22102016);
  A.invy[0] = (float*)(w + 22110208);
  A.invy[1] = (float*)(w + 22118400);
  A.invy[2] = (float*)(w + 22126592);
  unsigned* flags = (unsigned*)(w + 22134784);
  A.flagG = flags;            // 320
  A.flagC = flags + 320;      // 3*256
  A.flagH = flags + 320 + 768;  // 2*128
  A.outp = (float*)d_out;

  // zero flags every call (ws is not re-poisoned between graph replays)
  hipMemsetAsync(flags, 0, (320 + 768 + 256) * sizeof(unsigned), stream);

  void* kargs[] = { (void*)&A };
  hipLaunchCooperativeKernel((const void*)k_mega, dim3(256), dim3(256),
                             kargs, 0, stream);
}

// Round 6
// 106.521 us; speedup vs baseline: 3.1055x; 2.0600x over previous
//
#include <hip/hip_runtime.h>
#include <hip/hip_bf16.h>
#include <cstdint>
#include <cstddef>

#define IC 512     // in_caps
#define IDM 768    // in_dim
#define KC 16      // num_caps
#define NB 128     // batch
#define NOUT 1024  // KC*DC

typedef __attribute__((ext_vector_type(8))) short short8v;
typedef __attribute__((ext_vector_type(4))) float f32x4;

#define MFMA __builtin_amdgcn_mfma_f32_16x16x32_bf16

static __device__ __forceinline__ unsigned fbits(float x) {
  union { float f; unsigned u; } z; z.f = x; return z.u;
}
static __device__ __forceinline__ float bf_f(ushort u) {
  union { float f; unsigned u32; } z; z.u32 = ((unsigned)u) << 16; return z.f;
}
// truncation-based hi/lo split; residual ~2^-16 rel
static __device__ __forceinline__ void split2(float x, ushort& h, ushort& l) {
  h = (ushort)(fbits(x) >> 16);
  const float r = x - bf_f(h);
  l = (ushort)(fbits(r) >> 16);
}
static __device__ __forceinline__ void split8(const float* p, short8v& h, short8v& l) {
  const float4 x0 = *(const float4*)p;
  const float4 x1 = *(const float4*)(p + 4);
  const float xs[8] = {x0.x, x0.y, x0.z, x0.w, x1.x, x1.y, x1.z, x1.w};
  #pragma unroll
  for (int j = 0; j < 8; ++j) {
    ushort hh, ll; split2(xs[j], hh, ll);
    h[j] = (short)hh; l[j] = (short)ll;
  }
}

struct KArgs {
  const float *m, *q, *Ww, *Wb;
  ushort *Hh, *Hl, *HTh, *HTl;          // hat_m [i][n] and [n][i], bf16 hi/lo
  float *Yf[3]; ushort *Yh[3], *Yl[3];  // y per round
  float *Vf[2]; ushort *Vh[2], *Vl[2];  // vsum per round
  ushort *Dh[3], *Dl[3];                // dsp per round [b][k*512+i]
  float *summ, *invx;                   // hat_m row stats
  float *sy[3], *invy[3];               // y row stats per round
  float *outp;
};

// ---- GEMM tile: 32 rows x 64 cols, f32 loads + in-register hi/lo split ----
static __device__ __forceinline__ void gemm_tile(
    const KArgs& A, int tile, int t, float (*sred)[2][32])
{
  const int w = t >> 6, L = t & 63, c = L & 15, g = L >> 4;
  const int wr = w >> 1, wc = w & 1;
  const int rt = tile >> 4, nt = tile & 15;
  const int r0 = rt * 32, n0 = nt * 64;
  const int arow = r0 + wr * 16 + c;
  const int bcol = n0 + wc * 32 + c;
  const float* asrc = (arow < IC) ? (A.m + (size_t)arow * IDM)
                                  : (A.q + (size_t)(arow - IC) * IDM);
  const float* b0src = A.Ww + (size_t)bcol * IDM;
  const float* b1src = A.Ww + (size_t)(bcol + 16) * IDM;

  f32x4 acc0 = {}, acc1 = {};
  #pragma unroll 2
  for (int kb = 0; kb < IDM; kb += 32) {
    short8v ah, al, bh0, bl0, bh1, bl1;
    split8(asrc + kb + g * 8, ah, al);
    split8(b0src + kb + g * 8, bh0, bl0);
    split8(b1src + kb + g * 8, bh1, bl1);
    acc0 = MFMA(ah, bh0, acc0, 0, 0, 0);
    acc0 = MFMA(ah, bl0, acc0, 0, 0, 0);
    acc0 = MFMA(al, bh0, acc0, 0, 0, 0);
    acc1 = MFMA(ah, bh1, acc1, 0, 0, 0);
    acc1 = MFMA(ah, bl1, acc1, 0, 0, 0);
    acc1 = MFMA(al, bh1, acc1, 0, 0, 0);
  }

  const float bias0 = A.Wb[bcol];
  const float bias1 = A.Wb[bcol + 16];
  float v0s[4], v1s[4];
  #pragma unroll
  for (int j = 0; j < 4; ++j) { v0s[j] = acc0[j] + bias0; v1s[j] = acc1[j] + bias1; }

  #pragma unroll
  for (int j = 0; j < 4; ++j) {
    float s = v0s[j] + v1s[j];
    float q2 = v0s[j] * v0s[j] + v1s[j] * v1s[j];
    #pragma unroll
    for (int off = 1; off < 16; off <<= 1) {
      s += __shfl_xor(s, off);
      q2 += __shfl_xor(q2, off);
    }
    if (c == 0) {
      sred[wc][0][wr * 16 + 4 * g + j] = s;
      sred[wc][1][wr * 16 + 4 * g + j] = q2;
    }
  }

  ushort h0[4], l0[4], h1[4], l1[4];
  #pragma unroll
  for (int j = 0; j < 4; ++j) { split2(v0s[j], h0[j], l0[j]); split2(v1s[j], h1[j], l1[j]); }

  const int rowb = r0 + wr * 16 + 4 * g;
  if (rowb < IC) {
    #pragma unroll
    for (int j = 0; j < 4; ++j) {
      const size_t r = (size_t)(rowb + j) * NOUT;
      A.Hh[r + bcol] = h0[j]; A.Hl[r + bcol] = l0[j];
      A.Hh[r + bcol + 16] = h1[j]; A.Hl[r + bcol + 16] = l1[j];
    }
    *(ushort4*)&A.HTh[(size_t)bcol * 512 + rowb] = make_ushort4(h0[0], h0[1], h0[2], h0[3]);
    *(ushort4*)&A.HTl[(size_t)bcol * 512 + rowb] = make_ushort4(l0[0], l0[1], l0[2], l0[3]);
    *(ushort4*)&A.HTh[(size_t)(bcol + 16) * 512 + rowb] = make_ushort4(h1[0], h1[1], h1[2], h1[3]);
    *(ushort4*)&A.HTl[(size_t)(bcol + 16) * 512 + rowb] = make_ushort4(l1[0], l1[1], l1[2], l1[3]);
  } else {
    #pragma unroll
    for (int j = 0; j < 4; ++j) {
      const size_t r = (size_t)(rowb + j - IC) * NOUT;
      A.Yf[0][r + bcol] = v0s[j]; A.Yf[0][r + bcol + 16] = v1s[j];
      A.Yh[0][r + bcol] = h0[j]; A.Yl[0][r + bcol] = l0[j];
      A.Yh[0][r + bcol + 16] = h1[j]; A.Yl[0][r + bcol + 16] = l1[j];
    }
  }
  __syncthreads();
  if (t < 32) {
    const int row = r0 + t;
    const float s = sred[0][0][t] + sred[1][0][t];
    const float q2 = sred[0][1][t] + sred[1][1][t];
    const float inv = rsqrtf(q2 - s * s * (1.0f / 64.0f));
    if (row < IC) {
      A.summ[row * KC + nt] = s;
      A.invx[row * KC + nt] = inv;
    } else {
      A.sy[0][(row - IC) * KC + nt] = s;
      A.invy[0][(row - IC) * KC + nt] = inv;
    }
  }
}

// ---- corr + softmax fused (block = 16i x 16b, waves split k) ----
template <int RR>   // 0: round 0 (uniform d, no a-dot); 1: rounds 1,2
static __device__ __forceinline__ void corr_sm(
    const KArgs& A, int bid, int t,
    const ushort* Yh, const ushort* Yl,
    const ushort* Vh, const ushort* Vl,
    const float* sy, const float* invy,
    ushort* Dh, ushort* Dl,
    float (*p_lds)[256], float (*a_lds)[256])
{
  const int w = t >> 6, L = t & 63, c = L & 15, g = L >> 4;
  const int it = bid >> 3, bt = bid & 7;
  const int i0 = it * 16, b0 = bt * 16;

  #pragma unroll
  for (int kk4 = 0; kk4 < 4; ++kk4) {
    const int k = kk4 * 4 + w;
    const size_t koff = (size_t)k * 64 + g * 8;
    const ushort* pAh = A.Hh + (size_t)(i0 + c) * NOUT + koff;
    const ushort* pAl = A.Hl + (size_t)(i0 + c) * NOUT + koff;
    const ushort* pYh = Yh + (size_t)(b0 + c) * NOUT + koff;
    const ushort* pYl = Yl + (size_t)(b0 + c) * NOUT + koff;
    const ushort* pVh = Vh + (size_t)(b0 + c) * NOUT + koff;
    const ushort* pVl = Vl + (size_t)(b0 + c) * NOUT + koff;

    f32x4 P = {}, Aa = {};
    #pragma unroll
    for (int ks = 0; ks < 64; ks += 32) {
      const short8v ah = *(const short8v*)(pAh + ks);
      const short8v al = *(const short8v*)(pAl + ks);
      const short8v yh = *(const short8v*)(pYh + ks);
      const short8v yl = *(const short8v*)(pYl + ks);
      P = MFMA(ah, yh, P, 0, 0, 0);
      P = MFMA(ah, yl, P, 0, 0, 0);
      P = MFMA(al, yh, P, 0, 0, 0);
      if (RR) {
        const short8v vh = *(const short8v*)(pVh + ks);
        const short8v vl = *(const short8v*)(pVl + ks);
        Aa = MFMA(ah, vh, Aa, 0, 0, 0);
        Aa = MFMA(ah, vl, Aa, 0, 0, 0);
        Aa = MFMA(al, vh, Aa, 0, 0, 0);
      }
    }
    const float syb = sy[(b0 + c) * KC + k];
    const float iyb = invy[(b0 + c) * KC + k];
    f32x4 pv;
    #pragma unroll
    for (int j = 0; j < 4; ++j) {
      const int i = i0 + 4 * g + j;
      pv[j] = tanhf((P[j] - A.summ[i * KC + k] * syb * (1.0f / 64.0f))
                    * A.invx[i * KC + k] * iyb);
    }
    *(f32x4*)&p_lds[k][c * 16 + 4 * g] = pv;
    if (RR) *(f32x4*)&a_lds[k][c * 16 + 4 * g] = Aa;
  }
  __syncthreads();

  // softmax over k per (b_local = t>>4, i_local = t&15), dsp -> bf16 hi/lo
  const int bl = t >> 4, il = t & 15;
  const size_t dbase = (size_t)(b0 + bl) * 8192 + (size_t)(i0 + il);
  if (RR == 0) {
    #pragma unroll
    for (int k = 0; k < 16; ++k) {
      const float x = 0.0625f - p_lds[k][t];
      ushort h, l2; split2(x, h, l2);
      Dh[dbase + (size_t)k * 512] = h;
      Dl[dbase + (size_t)k * 512] = l2;
    }
  } else {
    float av[16];
    float mx = -1e30f;
    #pragma unroll
    for (int k = 0; k < 16; ++k) { av[k] = a_lds[k][t]; mx = fmaxf(mx, av[k]); }
    float s = 0.f;
    #pragma unroll
    for (int k = 0; k < 16; ++k) { av[k] = __expf(av[k] - mx); s += av[k]; }
    const float inv = 1.0f / s;
    #pragma unroll
    for (int k = 0; k < 16; ++k) {
      const float x = av[k] * inv - p_lds[k][t];
      ushort h, l2; split2(x, h, l2);
      Dh[dbase + (size_t)k * 512] = h;
      Dl[dbase + (size_t)k * 512] = l2;
    }
  }
}

// ---- hat_v via MFMA + squash + y/vsum update (block = (k, 16 b)) ----
template <int R>   // 0: vsum=v; 1: vsum+=v; 2: final (outp only)
static __device__ __forceinline__ void hatv_body(
    const KArgs& A, int bid, int t,
    const ushort* Dh, const ushort* Dl,
    const float* Yfin, float* Yfout, ushort* Yhout, ushort* Ylout,
    const float* Vfin, float* Vfout, ushort* Vhout, ushort* Vlout,
    float* syout, float* invyout,
    float (*red)[4][16], float* sscale)
{
  const int w = t >> 6, L = t & 63, c = L & 15, g = L >> 4;
  const int k = bid & 15;
  const int b0 = (bid >> 4) * 16;

  const ushort* pAh = Dh + (size_t)(b0 + c) * 8192 + (size_t)k * 512 + g * 8;
  const ushort* pAl = Dl + (size_t)(b0 + c) * 8192 + (size_t)k * 512 + g * 8;
  const ushort* pBh = A.HTh + (size_t)(k * 64 + w * 16 + c) * 512 + g * 8;
  const ushort* pBl = A.HTl + (size_t)(k * 64 + w * 16 + c) * 512 + g * 8;

  f32x4 acc = {};
  #pragma unroll 4
  for (int i = 0; i < 512; i += 32) {
    const short8v ah = *(const short8v*)(pAh + i);
    const short8v al = *(const short8v*)(pAl + i);
    const short8v bh = *(const short8v*)(pBh + i);
    const short8v bl = *(const short8v*)(pBl + i);
    acc = MFMA(ah, bh, acc, 0, 0, 0);
    acc = MFMA(ah, bl, acc, 0, 0, 0);
    acc = MFMA(al, bh, acc, 0, 0, 0);
  }

  float sq[4];
  #pragma unroll
  for (int j = 0; j < 4; ++j) {
    sq[j] = acc[j] * acc[j];
    #pragma unroll
    for (int off = 1; off < 16; off <<= 1) sq[j] += __shfl_xor(sq[j], off);
  }
  if (c == 0) {
    #pragma unroll
    for (int j = 0; j < 4; ++j) red[0][w][4 * g + j] = sq[j];
  }
  __syncthreads();
  if (t < 16) {
    const float s = red[0][0][t] + red[0][1][t] + red[0][2][t] + red[0][3][t];
    sscale[t] = (s / (1.0f + s)) * rsqrtf(s + 1e-8f);
  }
  __syncthreads();

  const int d = w * 16 + c;
  float s1[4], s2[4];
  #pragma unroll
  for (int j = 0; j < 4; ++j) {
    const int bl_ = 4 * g + j;
    const int b = b0 + bl_;
    const float v = acc[j] * sscale[bl_];
    const size_t idx = (size_t)b * NOUT + (size_t)k * 64 + d;
    if (R == 2) {
      A.outp[idx] = v;
    } else {
      const float vs = (R == 0) ? v : (Vfin[idx] + v);
      Vfout[idx] = vs;
      ushort h, l2;
      split2(vs, h, l2); Vhout[idx] = h; Vlout[idx] = l2;
      const float yn = (Yfin[idx] + v) * 0.5f;
      Yfout[idx] = yn;
      split2(yn, h, l2); Yhout[idx] = h; Ylout[idx] = l2;
      s1[j] = yn; s2[j] = yn * yn;
    }
  }
  if (R != 2) {
    #pragma unroll
    for (int j = 0; j < 4; ++j) {
      #pragma unroll
      for (int off = 1; off < 16; off <<= 1) {
        s1[j] += __shfl_xor(s1[j], off);
        s2[j] += __shfl_xor(s2[j], off);
      }
    }
    if (c == 0) {
      #pragma unroll
      for (int j = 0; j < 4; ++j) {
        red[1][w][4 * g + j] = s1[j];
        red[2][w][4 * g + j] = s2[j];
      }
    }
    __syncthreads();
    if (t < 16) {
      const float s = red[1][0][t] + red[1][1][t] + red[1][2][t] + red[1][3][t];
      const float q2 = red[2][0][t] + red[2][1][t] + red[2][2][t] + red[2][3][t];
      syout[(b0 + t) * KC + k] = s;
      invyout[(b0 + t) * KC + k] = rsqrtf(q2 - s * s * (1.0f / 64.0f));
    }
  }
}

// ===================== standalone kernels =====================
__global__ __launch_bounds__(256) void k_gemm(KArgs A) {
  __shared__ float sred[2][2][32];
  gemm_tile(A, blockIdx.x, threadIdx.x, sred);
}

template <int R>
__global__ __launch_bounds__(256) void k_corr(KArgs A) {
  __shared__ float p_lds[16][256];
  __shared__ float a_lds[16][256];
  if (R == 0) {
    corr_sm<0>(A, blockIdx.x, threadIdx.x, A.Yh[0], A.Yl[0], A.Vh[0], A.Vl[0],
               A.sy[0], A.invy[0], A.Dh[0], A.Dl[0], p_lds, a_lds);
  } else if (R == 1) {
    corr_sm<1>(A, blockIdx.x, threadIdx.x, A.Yh[1], A.Yl[1], A.Vh[0], A.Vl[0],
               A.sy[1], A.invy[1], A.Dh[1], A.Dl[1], p_lds, a_lds);
  } else {
    corr_sm<1>(A, blockIdx.x, threadIdx.x, A.Yh[2], A.Yl[2], A.Vh[1], A.Vl[1],
               A.sy[2], A.invy[2], A.Dh[2], A.Dl[2], p_lds, a_lds);
  }
}

template <int R>
__global__ __launch_bounds__(256) void k_hatv(KArgs A) {
  __shared__ float red[3][4][16];
  __shared__ float sscale[16];
  if (R == 0) {
    hatv_body<0>(A, blockIdx.x, threadIdx.x, A.Dh[0], A.Dl[0],
                 A.Yf[0], A.Yf[1], A.Yh[1], A.Yl[1],
                 nullptr, A.Vf[0], A.Vh[0], A.Vl[0],
                 A.sy[1], A.invy[1], red, sscale);
  } else if (R == 1) {
    hatv_body<1>(A, blockIdx.x, threadIdx.x, A.Dh[1], A.Dl[1],
                 A.Yf[1], A.Yf[2], A.Yh[2], A.Yl[2],
                 A.Vf[0], A.Vf[1], A.Vh[1], A.Vl[1],
                 A.sy[2], A.invy[2], red, sscale);
  } else {
    hatv_body<2>(A, blockIdx.x, threadIdx.x, A.Dh[2], A.Dl[2],
                 nullptr, nullptr, nullptr, nullptr,
                 nullptr, nullptr, nullptr, nullptr,
                 nullptr, nullptr, red, sscale);
  }
}

// ===================== launch =====================
extern "C" void kernel_launch(void* const* d_in, const int* in_sizes, int n_in,
                              void* d_out, int out_size, void* d_ws, size_t ws_size,
                              hipStream_t stream) {
  char* w = (char*)d_ws;
  KArgs A;
  A.m  = (const float*)d_in[0];
  A.q  = (const float*)d_in[1];
  A.Ww = (const float*)d_in[2];
  A.Wb = (const float*)d_in[3];
  A.Hh  = (ushort*)(w + 0);
  A.Hl  = (ushort*)(w + 1048576);
  A.HTh = (ushort*)(w + 2097152);
  A.HTl = (ushort*)(w + 3145728);
  A.Yf[0] = (float*)(w + 4194304);
  A.Yf[1] = (float*)(w + 4718592);
  A.Yf[2] = (float*)(w + 5242880);
  A.Yh[0] = (ushort*)(w + 5767168);
  A.Yh[1] = (ushort*)(w + 6029312);
  A.Yh[2] = (ushort*)(w + 6291456);
  A.Yl[0] = (ushort*)(w + 6553600);
  A.Yl[1] = (ushort*)(w + 6815744);
  A.Yl[2] = (ushort*)(w + 7077888);
  A.Vf[0] = (float*)(w + 7340032);
  A.Vf[1] = (float*)(w + 7864320);
  A.Vh[0] = (ushort*)(w + 8388608);
  A.Vh[1] = (ushort*)(w + 8650752);
  A.Vl[0] = (ushort*)(w + 8912896);
  A.Vl[1] = (ushort*)(w + 9175040);
  A.Dh[0] = (ushort*)(w + 9437184);
  A.Dh[1] = (ushort*)(w + 11534336);
  A.Dh[2] = (ushort*)(w + 13631488);
  A.Dl[0] = (ushort*)(w + 15728640);
  A.Dl[1] = (ushort*)(w + 17825792);
  A.Dl[2] = (ushort*)(w + 19922944);
  A.summ = (float*)(w + 22020096);
  A.invx = (float*)(w + 22052864);
  A.sy[0]   = (float*)(w + 22085632);
  A.sy[1]   = (float*)(w + 22093824);
  A.sy[2]   = (float*)(w + 22102016);
  A.invy[0] = (float*)(w + 22110208);
  A.invy[1] = (float*)(w + 22118400);
  A.invy[2] = (float*)(w + 22126592);
  A.outp = (float*)d_out;

  k_gemm<<<320, 256, 0, stream>>>(A);
  k_corr<0><<<256, 256, 0, stream>>>(A);
  k_hatv<0><<<128, 256, 0, stream>>>(A);
  k_corr<1><<<256, 256, 0, stream>>>(A);
  k_hatv<1><<<128, 256, 0, stream>>>(A);
  k_corr<2><<<256, 256, 0, stream>>>(A);
  k_hatv<2><<<128, 256, 0, stream>>>(A);
}

// Round 7
// 78.505 us; speedup vs baseline: 4.2138x; 1.3569x over previous
//
#include <hip/hip_runtime.h>
#include <hip/hip_bf16.h>
#include <cstdint>
#include <cstddef>

#define IC 512     // in_caps
#define IDM 768    // in_dim
#define KC 16      // num_caps
#define NB 128     // batch
#define NOUT 1024  // KC*DC

typedef __attribute__((ext_vector_type(8))) short short8v;
typedef __attribute__((ext_vector_type(4))) float f32x4;

#define MFMA __builtin_amdgcn_mfma_f32_16x16x32_bf16

static __device__ __forceinline__ unsigned fbits(float x) {
  union { float f; unsigned u; } z; z.f = x; return z.u;
}
static __device__ __forceinline__ float bf_f(ushort u) {
  union { float f; unsigned u32; } z; z.u32 = ((unsigned)u) << 16; return z.f;
}
// round-to-nearest-even single bf16
static __device__ __forceinline__ ushort bf_rne(float x) {
  __hip_bfloat16 h = __float2bfloat16(x);
  return *reinterpret_cast<ushort*>(&h);
}
// truncation hi/lo split (GEMM input path only)
static __device__ __forceinline__ void split2(float x, ushort& h, ushort& l) {
  h = (ushort)(fbits(x) >> 16);
  const float r = x - bf_f(h);
  l = (ushort)(fbits(r) >> 16);
}
static __device__ __forceinline__ void split8(const float* p, short8v& h, short8v& l) {
  const float4 x0 = *(const float4*)p;
  const float4 x1 = *(const float4*)(p + 4);
  const float xs[8] = {x0.x, x0.y, x0.z, x0.w, x1.x, x1.y, x1.z, x1.w};
  #pragma unroll
  for (int j = 0; j < 8; ++j) {
    ushort hh, ll; split2(xs[j], hh, ll);
    h[j] = (short)hh; l[j] = (short)ll;
  }
}

struct KArgs {
  const float *m, *q, *Ww, *Wb;
  ushort *Hb, *HTb;                     // hat_m bf16 [i][n] and [n][i]
  float *Yf[3]; ushort *Yb[3];          // y per round (f32 chain + bf16 view)
  float *Vf[2]; ushort *Vb[2];          // vsum per round
  ushort *Db[3];                        // dsp per round [b][k*512+i], bf16
  float *summT, *invxT;                 // hat_m row stats, [k][i] transposed
  float *syT[3], *invyT[3];             // y row stats, [k][b] transposed
  float *outp;
};

// ===================== K1: GEMM (hi/lo f32-accurate) + bf16 epilogue ============
__global__ __launch_bounds__(256) void k_gemm(KArgs A)
{
  __shared__ float sred[2][2][32];
  const int t = threadIdx.x;
  const int tile = blockIdx.x;
  const int w = t >> 6, L = t & 63, c = L & 15, g = L >> 4;
  const int wr = w >> 1, wc = w & 1;
  const int rt = tile >> 4, nt = tile & 15;   // tile%8 = nt%8 -> Ww col-local per XCD
  const int r0 = rt * 32, n0 = nt * 64;
  const int arow = r0 + wr * 16 + c;
  const int bcol = n0 + wc * 32 + c;
  const float* asrc = (arow < IC) ? (A.m + (size_t)arow * IDM)
                                  : (A.q + (size_t)(arow - IC) * IDM);
  const float* b0src = A.Ww + (size_t)bcol * IDM;
  const float* b1src = A.Ww + (size_t)(bcol + 16) * IDM;

  f32x4 acc0 = {}, acc1 = {};
  #pragma unroll 2
  for (int kb = 0; kb < IDM; kb += 32) {
    short8v ah, al, bh0, bl0, bh1, bl1;
    split8(asrc + kb + g * 8, ah, al);
    split8(b0src + kb + g * 8, bh0, bl0);
    split8(b1src + kb + g * 8, bh1, bl1);
    acc0 = MFMA(ah, bh0, acc0, 0, 0, 0);
    acc0 = MFMA(ah, bl0, acc0, 0, 0, 0);
    acc0 = MFMA(al, bh0, acc0, 0, 0, 0);
    acc1 = MFMA(ah, bh1, acc1, 0, 0, 0);
    acc1 = MFMA(ah, bl1, acc1, 0, 0, 0);
    acc1 = MFMA(al, bh1, acc1, 0, 0, 0);
  }

  const float bias0 = A.Wb[bcol];
  const float bias1 = A.Wb[bcol + 16];
  float v0s[4], v1s[4];
  #pragma unroll
  for (int j = 0; j < 4; ++j) { v0s[j] = acc0[j] + bias0; v1s[j] = acc1[j] + bias1; }

  #pragma unroll
  for (int j = 0; j < 4; ++j) {
    float s = v0s[j] + v1s[j];
    float q2 = v0s[j] * v0s[j] + v1s[j] * v1s[j];
    #pragma unroll
    for (int off = 1; off < 16; off <<= 1) {
      s += __shfl_xor(s, off);
      q2 += __shfl_xor(q2, off);
    }
    if (c == 0) {
      sred[wc][0][wr * 16 + 4 * g + j] = s;
      sred[wc][1][wr * 16 + 4 * g + j] = q2;
    }
  }

  ushort h0[4], h1[4];
  #pragma unroll
  for (int j = 0; j < 4; ++j) { h0[j] = bf_rne(v0s[j]); h1[j] = bf_rne(v1s[j]); }

  const int rowb = r0 + wr * 16 + 4 * g;
  if (rowb < IC) {
    #pragma unroll
    for (int j = 0; j < 4; ++j) {
      const size_t r = (size_t)(rowb + j) * NOUT;
      A.Hb[r + bcol] = h0[j];
      A.Hb[r + bcol + 16] = h1[j];
    }
    *(ushort4*)&A.HTb[(size_t)bcol * 512 + rowb] = make_ushort4(h0[0], h0[1], h0[2], h0[3]);
    *(ushort4*)&A.HTb[(size_t)(bcol + 16) * 512 + rowb] = make_ushort4(h1[0], h1[1], h1[2], h1[3]);
  } else {
    #pragma unroll
    for (int j = 0; j < 4; ++j) {
      const size_t r = (size_t)(rowb + j - IC) * NOUT;
      A.Yf[0][r + bcol] = v0s[j]; A.Yf[0][r + bcol + 16] = v1s[j];
      A.Yb[0][r + bcol] = h0[j]; A.Yb[0][r + bcol + 16] = h1[j];
    }
  }
  __syncthreads();
  if (t < 32) {
    const int row = r0 + t;
    const float s = sred[0][0][t] + sred[1][0][t];
    const float q2 = sred[0][1][t] + sred[1][1][t];
    const float inv = rsqrtf(q2 - s * s * (1.0f / 64.0f));
    if (row < IC) {
      A.summT[nt * 512 + row] = s;
      A.invxT[nt * 512 + row] = inv;
    } else {
      A.syT[0][nt * 128 + (row - IC)] = s;
      A.invyT[0][nt * 128 + (row - IC)] = inv;
    }
  }
}

// ===================== K2: corr + softmax (1024 thr, wave = one k) ==============
// Block: (i-tile 16, b-tile 16); grid 256, it = bid&31 so it%8 -> XCD (H local).
template <int RR>   // 0: round 0 (uniform d, no a-dot); 1: rounds 1,2
__global__ __launch_bounds__(1024) void k_corr(KArgs A)
{
  __shared__ float p_lds[16][256];
  __shared__ float a_lds[16][256];
  const int t = threadIdx.x;
  const int bid = blockIdx.x;
  const int it = bid & 31, bt = bid >> 5;
  const int i0 = it * 16, b0 = bt * 16;
  const int k = t >> 6, L = t & 63, c = L & 15, g = L >> 4;

  const ushort* Yb = A.Yb[RR == 0 ? 0 : (RR == 1 ? 1 : 2)];
  const ushort* Vb = A.Vb[RR == 2 ? 1 : 0];
  const float* syT = A.syT[RR == 0 ? 0 : (RR == 1 ? 1 : 2)];
  const float* invyT = A.invyT[RR == 0 ? 0 : (RR == 1 ? 1 : 2)];
  ushort* Db = A.Db[RR == 0 ? 0 : (RR == 1 ? 1 : 2)];

  const size_t koff = (size_t)k * 64 + g * 8;
  const ushort* pH = A.Hb + (size_t)(i0 + c) * NOUT + koff;
  const ushort* pY = Yb + (size_t)(b0 + c) * NOUT + koff;
  const ushort* pV = Vb + (size_t)(b0 + c) * NOUT + koff;

  f32x4 P = {}, Aa = {};
  #pragma unroll
  for (int ks = 0; ks < 64; ks += 32) {
    const short8v ah = *(const short8v*)(pH + ks);
    const short8v yh = *(const short8v*)(pY + ks);
    P = MFMA(ah, yh, P, 0, 0, 0);
    if (RR) {
      const short8v vh = *(const short8v*)(pV + ks);
      Aa = MFMA(ah, vh, Aa, 0, 0, 0);
    }
  }

  const float syb = syT[k * 128 + b0 + c];
  const float iyb = invyT[k * 128 + b0 + c];
  const f32x4 sm4 = *(const f32x4*)&A.summT[k * 512 + i0 + 4 * g];
  const f32x4 ix4 = *(const f32x4*)&A.invxT[k * 512 + i0 + 4 * g];
  f32x4 pv;
  #pragma unroll
  for (int j = 0; j < 4; ++j)
    pv[j] = tanhf((P[j] - sm4[j] * syb * (1.0f / 64.0f)) * ix4[j] * iyb);
  *(f32x4*)&p_lds[k][c * 16 + 4 * g] = pv;
  if (RR) *(f32x4*)&a_lds[k][c * 16 + 4 * g] = Aa;
  __syncthreads();

  if (t < 256) {
    const int bl = t >> 4, il = t & 15;
    const size_t dbase = (size_t)(b0 + bl) * 8192 + (size_t)(i0 + il);
    if (RR == 0) {
      #pragma unroll
      for (int kk = 0; kk < 16; ++kk)
        Db[dbase + (size_t)kk * 512] = bf_rne(0.0625f - p_lds[kk][t]);
    } else {
      float av[16];
      float mx = -1e30f;
      #pragma unroll
      for (int kk = 0; kk < 16; ++kk) { av[kk] = a_lds[kk][t]; mx = fmaxf(mx, av[kk]); }
      float s = 0.f;
      #pragma unroll
      for (int kk = 0; kk < 16; ++kk) { av[kk] = __expf(av[kk] - mx); s += av[kk]; }
      const float inv = 1.0f / s;
      #pragma unroll
      for (int kk = 0; kk < 16; ++kk)
        Db[dbase + (size_t)kk * 512] = bf_rne(av[kk] * inv - p_lds[kk][t]);
    }
  }
}

// ===================== K3: hat_v MFMA + squash + y/vsum update ==================
// Block: (k, 16 b); grid 128, bid%8 = k%8 -> D/HT k-slices XCD-local.
template <int R>   // 0: vsum=v; 1: vsum+=v; 2: final (outp only)
__global__ __launch_bounds__(256) void k_hatv(KArgs A)
{
  __shared__ float red[3][4][16];
  __shared__ float sscale[16];
  const int t = threadIdx.x;
  const int bid = blockIdx.x;
  const int w = t >> 6, L = t & 63, c = L & 15, g = L >> 4;
  const int k = bid & 15;
  const int b0 = (bid >> 4) * 16;

  const ushort* Db = A.Db[R];
  const float* Yfin = (R == 2) ? nullptr : A.Yf[R];
  float* Yfout = (R == 2) ? nullptr : A.Yf[R + 1];
  ushort* Ybout = (R == 2) ? nullptr : A.Yb[R + 1];
  const float* Vfin = (R == 1) ? A.Vf[0] : nullptr;
  float* Vfout = (R == 2) ? nullptr : A.Vf[R];
  ushort* Vbout = (R == 2) ? nullptr : A.Vb[R];
  float* syout = (R == 2) ? nullptr : A.syT[R + 1];
  float* invyout = (R == 2) ? nullptr : A.invyT[R + 1];

  const ushort* pA = Db + (size_t)(b0 + c) * 8192 + (size_t)k * 512 + g * 8;
  const ushort* pB = A.HTb + (size_t)(k * 64 + w * 16 + c) * 512 + g * 8;

  f32x4 acc = {};
  #pragma unroll 8
  for (int i = 0; i < 512; i += 32) {
    const short8v ab = *(const short8v*)(pA + i);
    const short8v bb = *(const short8v*)(pB + i);
    acc = MFMA(ab, bb, acc, 0, 0, 0);
  }

  float sq[4];
  #pragma unroll
  for (int j = 0; j < 4; ++j) {
    sq[j] = acc[j] * acc[j];
    #pragma unroll
    for (int off = 1; off < 16; off <<= 1) sq[j] += __shfl_xor(sq[j], off);
  }
  if (c == 0) {
    #pragma unroll
    for (int j = 0; j < 4; ++j) red[0][w][4 * g + j] = sq[j];
  }
  __syncthreads();
  if (t < 16) {
    const float s = red[0][0][t] + red[0][1][t] + red[0][2][t] + red[0][3][t];
    sscale[t] = (s / (1.0f + s)) * rsqrtf(s + 1e-8f);
  }
  __syncthreads();

  const int d = w * 16 + c;
  float s1[4], s2[4];
  #pragma unroll
  for (int j = 0; j < 4; ++j) {
    const int bl_ = 4 * g + j;
    const int b = b0 + bl_;
    const float v = acc[j] * sscale[bl_];
    const size_t idx = (size_t)b * NOUT + (size_t)k * 64 + d;
    if (R == 2) {
      A.outp[idx] = v;
    } else {
      const float vs = (R == 0) ? v : (Vfin[idx] + v);
      Vfout[idx] = vs;
      Vbout[idx] = bf_rne(vs);
      const float yn = (Yfin[idx] + v) * 0.5f;
      Yfout[idx] = yn;
      Ybout[idx] = bf_rne(yn);
      s1[j] = yn; s2[j] = yn * yn;
    }
  }
  if (R != 2) {
    #pragma unroll
    for (int j = 0; j < 4; ++j) {
      #pragma unroll
      for (int off = 1; off < 16; off <<= 1) {
        s1[j] += __shfl_xor(s1[j], off);
        s2[j] += __shfl_xor(s2[j], off);
      }
    }
    if (c == 0) {
      #pragma unroll
      for (int j = 0; j < 4; ++j) {
        red[1][w][4 * g + j] = s1[j];
        red[2][w][4 * g + j] = s2[j];
      }
    }
    __syncthreads();
    if (t < 16) {
      const float s = red[1][0][t] + red[1][1][t] + red[1][2][t] + red[1][3][t];
      const float q2 = red[2][0][t] + red[2][1][t] + red[2][2][t] + red[2][3][t];
      syout[k * 128 + b0 + t] = s;
      invyout[k * 128 + b0 + t] = rsqrtf(q2 - s * s * (1.0f / 64.0f));
    }
  }
}

// ===================== launch =====================
extern "C" void kernel_launch(void* const* d_in, const int* in_sizes, int n_in,
                              void* d_out, int out_size, void* d_ws, size_t ws_size,
                              hipStream_t stream) {
  char* w = (char*)d_ws;
  KArgs A;
  A.m  = (const float*)d_in[0];
  A.q  = (const float*)d_in[1];
  A.Ww = (const float*)d_in[2];
  A.Wb = (const float*)d_in[3];
  A.Hb   = (ushort*)(w + 0);          // 512*1024*2 = 1048576
  A.HTb  = (ushort*)(w + 1048576);    // 1048576
  A.Yf[0] = (float*)(w + 2097152);    // 524288 each
  A.Yf[1] = (float*)(w + 2621440);
  A.Yf[2] = (float*)(w + 3145728);
  A.Yb[0] = (ushort*)(w + 3670016);   // 262144 each
  A.Yb[1] = (ushort*)(w + 3932160);
  A.Yb[2] = (ushort*)(w + 4194304);
  A.Vf[0] = (float*)(w + 4456448);    // 524288 each
  A.Vf[1] = (float*)(w + 4980736);
  A.Vb[0] = (ushort*)(w + 5505024);   // 262144 each
  A.Vb[1] = (ushort*)(w + 5767168);
  A.Db[0] = (ushort*)(w + 6029312);   // 2097152 each
  A.Db[1] = (ushort*)(w + 8126464);
  A.Db[2] = (ushort*)(w + 10223616);
  A.summT = (float*)(w + 12320768);   // 32768
  A.invxT = (float*)(w + 12353536);   // 32768
  A.syT[0]   = (float*)(w + 12386304);  // 8192 each
  A.syT[1]   = (float*)(w + 12394496);
  A.syT[2]   = (float*)(w + 12402688);
  A.invyT[0] = (float*)(w + 12410880);
  A.invyT[1] = (float*)(w + 12419072);
  A.invyT[2] = (float*)(w + 12427264);
  A.outp = (float*)d_out;

  k_gemm<<<320, 256, 0, stream>>>(A);
  k_corr<0><<<256, 1024, 0, stream>>>(A);
  k_hatv<0><<<128, 256, 0, stream>>>(A);
  k_corr<1><<<256, 1024, 0, stream>>>(A);
  k_hatv<1><<<128, 256, 0, stream>>>(A);
  k_corr<2><<<256, 1024, 0, stream>>>(A);
  k_hatv<2><<<128, 256, 0, stream>>>(A);
}

// Round 8
// 78.016 us; speedup vs baseline: 4.2402x; 1.0063x over previous
//
#include <hip/hip_runtime.h>
#include <hip/hip_bf16.h>
#include <cstdint>
#include <cstddef>

#define IC 512     // in_caps
#define IDM 768    // in_dim
#define KC 16      // num_caps
#define NB 128     // batch
#define NOUT 1024  // KC*DC

typedef __attribute__((ext_vector_type(8))) short short8v;
typedef __attribute__((ext_vector_type(4))) float f32x4;

#define MFMA __builtin_amdgcn_mfma_f32_16x16x32_bf16

static __device__ __forceinline__ unsigned fbits(float x) {
  union { float f; unsigned u; } z; z.f = x; return z.u;
}
static __device__ __forceinline__ float bf_f(ushort u) {
  union { float f; unsigned u32; } z; z.u32 = ((unsigned)u) << 16; return z.f;
}
// round-to-nearest-even single bf16
static __device__ __forceinline__ ushort bf_rne(float x) {
  __hip_bfloat16 h = __float2bfloat16(x);
  return *reinterpret_cast<ushort*>(&h);
}
// truncation hi/lo split (GEMM input path only)
static __device__ __forceinline__ void split2(float x, ushort& h, ushort& l) {
  h = (ushort)(fbits(x) >> 16);
  const float r = x - bf_f(h);
  l = (ushort)(fbits(r) >> 16);
}
static __device__ __forceinline__ void split8(const float* p, short8v& h, short8v& l) {
  const float4 x0 = *(const float4*)p;
  const float4 x1 = *(const float4*)(p + 4);
  const float xs[8] = {x0.x, x0.y, x0.z, x0.w, x1.x, x1.y, x1.z, x1.w};
  #pragma unroll
  for (int j = 0; j < 8; ++j) {
    ushort hh, ll; split2(xs[j], hh, ll);
    h[j] = (short)hh; l[j] = (short)ll;
  }
}

struct KArgs {
  const float *m, *q, *Ww, *Wb;
  ushort *Hb, *HTb;                     // hat_m bf16 [i][n] and [n][i]
  ushort *Yb[3];                        // y per round, bf16 chain
  ushort *Vb[2];                        // vsum per round, bf16 chain
  ushort *Db[3];                        // dsp per round [b][k*512+i], bf16
  float *summT, *invxT;                 // hat_m row stats (of bf16 values), [k][i]
  float *syT[3], *invyT[3];             // y row stats (of bf16 values), [k][b]
  float *outp;
};

// ===================== K1: GEMM (hi/lo f32-accurate) + bf16 epilogue ============
// 2D XCD partition: region = bid%8 owns a 10(rt) x 4(nt) tile patch, so each
// XCD L2 fetches 320 A-rows + 256 Ww-cols (14.2 MB total vs 18.9 nt-local).
__global__ __launch_bounds__(256) void k_gemm(KArgs A)
{
  __shared__ float sred[2][2][32];
  const int t = threadIdx.x;
  const int bid = blockIdx.x;
  const int region = bid & 7, idx = bid >> 3;
  const int rt = (region & 1) * 10 + (idx % 10);
  const int nt = (region >> 1) * 4 + (idx / 10);
  const int w = t >> 6, L = t & 63, c = L & 15, g = L >> 4;
  const int wr = w >> 1, wc = w & 1;
  const int r0 = rt * 32, n0 = nt * 64;
  const int arow = r0 + wr * 16 + c;
  const int bcol = n0 + wc * 32 + c;
  const float* asrc = (arow < IC) ? (A.m + (size_t)arow * IDM)
                                  : (A.q + (size_t)(arow - IC) * IDM);
  const float* b0src = A.Ww + (size_t)bcol * IDM;
  const float* b1src = A.Ww + (size_t)(bcol + 16) * IDM;

  f32x4 acc0 = {}, acc1 = {};
  #pragma unroll 2
  for (int kb = 0; kb < IDM; kb += 32) {
    short8v ah, al, bh0, bl0, bh1, bl1;
    split8(asrc + kb + g * 8, ah, al);
    split8(b0src + kb + g * 8, bh0, bl0);
    split8(b1src + kb + g * 8, bh1, bl1);
    acc0 = MFMA(ah, bh0, acc0, 0, 0, 0);
    acc0 = MFMA(ah, bl0, acc0, 0, 0, 0);
    acc0 = MFMA(al, bh0, acc0, 0, 0, 0);
    acc1 = MFMA(ah, bh1, acc1, 0, 0, 0);
    acc1 = MFMA(ah, bl1, acc1, 0, 0, 0);
    acc1 = MFMA(al, bh1, acc1, 0, 0, 0);
  }

  const float bias0 = A.Wb[bcol];
  const float bias1 = A.Wb[bcol + 16];
  ushort h0[4], h1[4];
  float r0s[4], r1s[4];                 // bf16-rounded values (stats source)
  #pragma unroll
  for (int j = 0; j < 4; ++j) {
    h0[j] = bf_rne(acc0[j] + bias0); r0s[j] = bf_f(h0[j]);
    h1[j] = bf_rne(acc1[j] + bias1); r1s[j] = bf_f(h1[j]);
  }

  #pragma unroll
  for (int j = 0; j < 4; ++j) {
    float s = r0s[j] + r1s[j];
    float q2 = r0s[j] * r0s[j] + r1s[j] * r1s[j];
    #pragma unroll
    for (int off = 1; off < 16; off <<= 1) {
      s += __shfl_xor(s, off);
      q2 += __shfl_xor(q2, off);
    }
    if (c == 0) {
      sred[wc][0][wr * 16 + 4 * g + j] = s;
      sred[wc][1][wr * 16 + 4 * g + j] = q2;
    }
  }

  const int rowb = r0 + wr * 16 + 4 * g;
  if (rowb < IC) {
    #pragma unroll
    for (int j = 0; j < 4; ++j) {
      const size_t r = (size_t)(rowb + j) * NOUT;
      A.Hb[r + bcol] = h0[j];
      A.Hb[r + bcol + 16] = h1[j];
    }
    *(ushort4*)&A.HTb[(size_t)bcol * 512 + rowb] = make_ushort4(h0[0], h0[1], h0[2], h0[3]);
    *(ushort4*)&A.HTb[(size_t)(bcol + 16) * 512 + rowb] = make_ushort4(h1[0], h1[1], h1[2], h1[3]);
  } else {
    #pragma unroll
    for (int j = 0; j < 4; ++j) {
      const size_t r = (size_t)(rowb + j - IC) * NOUT;
      A.Yb[0][r + bcol] = h0[j];
      A.Yb[0][r + bcol + 16] = h1[j];
    }
  }
  __syncthreads();
  if (t < 32) {
    const int row = r0 + t;
    const float s = sred[0][0][t] + sred[1][0][t];
    const float q2 = sred[0][1][t] + sred[1][1][t];
    const float inv = rsqrtf(q2 - s * s * (1.0f / 64.0f));
    if (row < IC) {
      A.summT[nt * 512 + row] = s;
      A.invxT[nt * 512 + row] = inv;
    } else {
      A.syT[0][nt * 128 + (row - IC)] = s;
      A.invyT[0][nt * 128 + (row - IC)] = inv;
    }
  }
}

// ===================== K2: corr + softmax (1024 thr, wave = one k) ==============
// Block: (i-tile 16, b-tile 16); grid 256, it = bid&31 so it%8 -> XCD (H local).
template <int RR>   // 0: round 0 (uniform d, no a-dot); 1: rounds 1,2
__global__ __launch_bounds__(1024) void k_corr(KArgs A)
{
  __shared__ float p_lds[16][256];
  __shared__ float a_lds[16][256];
  const int t = threadIdx.x;
  const int bid = blockIdx.x;
  const int it = bid & 31, bt = bid >> 5;
  const int i0 = it * 16, b0 = bt * 16;
  const int k = t >> 6, L = t & 63, c = L & 15, g = L >> 4;

  const ushort* Yb = A.Yb[RR == 0 ? 0 : (RR == 1 ? 1 : 2)];
  const ushort* Vb = A.Vb[RR == 2 ? 1 : 0];
  const float* syT = A.syT[RR == 0 ? 0 : (RR == 1 ? 1 : 2)];
  const float* invyT = A.invyT[RR == 0 ? 0 : (RR == 1 ? 1 : 2)];
  ushort* Db = A.Db[RR == 0 ? 0 : (RR == 1 ? 1 : 2)];

  const size_t koff = (size_t)k * 64 + g * 8;
  const ushort* pH = A.Hb + (size_t)(i0 + c) * NOUT + koff;
  const ushort* pY = Yb + (size_t)(b0 + c) * NOUT + koff;
  const ushort* pV = Vb + (size_t)(b0 + c) * NOUT + koff;

  f32x4 P = {}, Aa = {};
  #pragma unroll
  for (int ks = 0; ks < 64; ks += 32) {
    const short8v ah = *(const short8v*)(pH + ks);
    const short8v yh = *(const short8v*)(pY + ks);
    P = MFMA(ah, yh, P, 0, 0, 0);
    if (RR) {
      const short8v vh = *(const short8v*)(pV + ks);
      Aa = MFMA(ah, vh, Aa, 0, 0, 0);
    }
  }

  const float syb = syT[k * 128 + b0 + c];
  const float iyb = invyT[k * 128 + b0 + c];
  const f32x4 sm4 = *(const f32x4*)&A.summT[k * 512 + i0 + 4 * g];
  const f32x4 ix4 = *(const f32x4*)&A.invxT[k * 512 + i0 + 4 * g];
  f32x4 pv;
  #pragma unroll
  for (int j = 0; j < 4; ++j)
    pv[j] = tanhf((P[j] - sm4[j] * syb * (1.0f / 64.0f)) * ix4[j] * iyb);
  *(f32x4*)&p_lds[k][c * 16 + 4 * g] = pv;
  if (RR) *(f32x4*)&a_lds[k][c * 16 + 4 * g] = Aa;
  __syncthreads();

  if (t < 256) {
    const int bl = t >> 4, il = t & 15;
    const size_t dbase = (size_t)(b0 + bl) * 8192 + (size_t)(i0 + il);
    if (RR == 0) {
      #pragma unroll
      for (int kk = 0; kk < 16; ++kk)
        Db[dbase + (size_t)kk * 512] = bf_rne(0.0625f - p_lds[kk][t]);
    } else {
      float av[16];
      float mx = -1e30f;
      #pragma unroll
      for (int kk = 0; kk < 16; ++kk) { av[kk] = a_lds[kk][t]; mx = fmaxf(mx, av[kk]); }
      float s = 0.f;
      #pragma unroll
      for (int kk = 0; kk < 16; ++kk) { av[kk] = __expf(av[kk] - mx); s += av[kk]; }
      const float inv = 1.0f / s;
      #pragma unroll
      for (int kk = 0; kk < 16; ++kk)
        Db[dbase + (size_t)kk * 512] = bf_rne(av[kk] * inv - p_lds[kk][t]);
    }
  }
}

// ===================== K3: hat_v MFMA + squash + y/vsum update ==================
// Block: (k, 16 b); grid 128, bid%8 = k%8 -> D/HT k-slices XCD-local.
template <int R>   // 0: vsum=v; 1: vsum+=v; 2: final (outp only)
__global__ __launch_bounds__(256) void k_hatv(KArgs A)
{
  __shared__ float red[3][4][16];
  __shared__ float sscale[16];
  const int t = threadIdx.x;
  const int bid = blockIdx.x;
  const int w = t >> 6, L = t & 63, c = L & 15, g = L >> 4;
  const int k = bid & 15;
  const int b0 = (bid >> 4) * 16;

  const ushort* Db = A.Db[R];
  const ushort* Ybin = (R == 2) ? nullptr : A.Yb[R];
  ushort* Ybout = (R == 2) ? nullptr : A.Yb[R + 1];
  const ushort* Vbin = (R == 1) ? A.Vb[0] : nullptr;
  ushort* Vbout = (R == 2) ? nullptr : A.Vb[R];
  float* syout = (R == 2) ? nullptr : A.syT[R + 1];
  float* invyout = (R == 2) ? nullptr : A.invyT[R + 1];

  const ushort* pA = Db + (size_t)(b0 + c) * 8192 + (size_t)k * 512 + g * 8;
  const ushort* pB = A.HTb + (size_t)(k * 64 + w * 16 + c) * 512 + g * 8;

  f32x4 acc = {};
  #pragma unroll 8
  for (int i = 0; i < 512; i += 32) {
    const short8v ab = *(const short8v*)(pA + i);
    const short8v bb = *(const short8v*)(pB + i);
    acc = MFMA(ab, bb, acc, 0, 0, 0);
  }

  float sq[4];
  #pragma unroll
  for (int j = 0; j < 4; ++j) {
    sq[j] = acc[j] * acc[j];
    #pragma unroll
    for (int off = 1; off < 16; off <<= 1) sq[j] += __shfl_xor(sq[j], off);
  }
  if (c == 0) {
    #pragma unroll
    for (int j = 0; j < 4; ++j) red[0][w][4 * g + j] = sq[j];
  }
  __syncthreads();
  if (t < 16) {
    const float s = red[0][0][t] + red[0][1][t] + red[0][2][t] + red[0][3][t];
    sscale[t] = (s / (1.0f + s)) * rsqrtf(s + 1e-8f);
  }
  __syncthreads();

  const int d = w * 16 + c;
  float s1[4], s2[4];
  #pragma unroll
  for (int j = 0; j < 4; ++j) {
    const int bl_ = 4 * g + j;
    const int b = b0 + bl_;
    const float v = acc[j] * sscale[bl_];
    const size_t idx = (size_t)b * NOUT + (size_t)k * 64 + d;
    if (R == 2) {
      A.outp[idx] = v;
    } else {
      const float vs = (R == 0) ? v : (bf_f(Vbin[idx]) + v);
      Vbout[idx] = bf_rne(vs);
      const float yn = (bf_f(Ybin[idx]) + v) * 0.5f;
      const ushort ynb = bf_rne(yn);
      Ybout[idx] = ynb;
      const float ynr = bf_f(ynb);   // stats of the bf16 y that corr will dot
      s1[j] = ynr; s2[j] = ynr * ynr;
    }
  }
  if (R != 2) {
    #pragma unroll
    for (int j = 0; j < 4; ++j) {
      #pragma unroll
      for (int off = 1; off < 16; off <<= 1) {
        s1[j] += __shfl_xor(s1[j], off);
        s2[j] += __shfl_xor(s2[j], off);
      }
    }
    if (c == 0) {
      #pragma unroll
      for (int j = 0; j < 4; ++j) {
        red[1][w][4 * g + j] = s1[j];
        red[2][w][4 * g + j] = s2[j];
      }
    }
    __syncthreads();
    if (t < 16) {
      const float s = red[1][0][t] + red[1][1][t] + red[1][2][t] + red[1][3][t];
      const float q2 = red[2][0][t] + red[2][1][t] + red[2][2][t] + red[2][3][t];
      syout[k * 128 + b0 + t] = s;
      invyout[k * 128 + b0 + t] = rsqrtf(q2 - s * s * (1.0f / 64.0f));
    }
  }
}

// ===================== launch =====================
extern "C" void kernel_launch(void* const* d_in, const int* in_sizes, int n_in,
                              void* d_out, int out_size, void* d_ws, size_t ws_size,
                              hipStream_t stream) {
  char* w = (char*)d_ws;
  KArgs A;
  A.m  = (const float*)d_in[0];
  A.q  = (const float*)d_in[1];
  A.Ww = (const float*)d_in[2];
  A.Wb = (const float*)d_in[3];
  A.Hb   = (ushort*)(w + 0);          // 1048576
  A.HTb  = (ushort*)(w + 1048576);    // 1048576
  A.Yb[0] = (ushort*)(w + 2097152);   // 262144 each
  A.Yb[1] = (ushort*)(w + 2359296);
  A.Yb[2] = (ushort*)(w + 2621440);
  A.Vb[0] = (ushort*)(w + 2883584);   // 262144 each
  A.Vb[1] = (ushort*)(w + 3145728);
  A.Db[0] = (ushort*)(w + 3407872);   // 2097152 each
  A.Db[1] = (ushort*)(w + 5505024);
  A.Db[2] = (ushort*)(w + 7602176);
  A.summT = (float*)(w + 9699328);    // 32768
  A.invxT = (float*)(w + 9732096);    // 32768
  A.syT[0]   = (float*)(w + 9764864);   // 8192 each
  A.syT[1]   = (float*)(w + 9773056);
  A.syT[2]   = (float*)(w + 9781248);
  A.invyT[0] = (float*)(w + 9789440);
  A.invyT[1] = (float*)(w + 9797632);
  A.invyT[2] = (float*)(w + 9805824);
  A.outp = (float*)d_out;

  k_gemm<<<320, 256, 0, stream>>>(A);
  k_corr<0><<<256, 1024, 0, stream>>>(A);
  k_hatv<0><<<128, 256, 0, stream>>>(A);
  k_corr<1><<<256, 1024, 0, stream>>>(A);
  k_hatv<1><<<128, 256, 0, stream>>>(A);
  k_corr<2><<<256, 1024, 0, stream>>>(A);
  k_hatv<2><<<128, 256, 0, stream>>>(A);
}

// Round 9
// 76.944 us; speedup vs baseline: 4.2993x; 1.0139x over previous
//
#include <hip/hip_runtime.h>
#include <hip/hip_bf16.h>
#include <cstdint>
#include <cstddef>

#define IC 512     // in_caps
#define IDM 768    // in_dim
#define KC 16      // num_caps
#define NB 128     // batch
#define NOUT 1024  // KC*DC

typedef __attribute__((ext_vector_type(8))) short short8v;
typedef __attribute__((ext_vector_type(4))) float f32x4;

#define MFMA __builtin_amdgcn_mfma_f32_16x16x32_bf16

static __device__ __forceinline__ unsigned fbits(float x) {
  union { float f; unsigned u; } z; z.f = x; return z.u;
}
static __device__ __forceinline__ float bf_f(ushort u) {
  union { float f; unsigned u32; } z; z.u32 = ((unsigned)u) << 16; return z.f;
}
// round-to-nearest-even single bf16
static __device__ __forceinline__ ushort bf_rne(float x) {
  __hip_bfloat16 h = __float2bfloat16(x);
  return *reinterpret_cast<ushort*>(&h);
}
// truncation hi/lo split (GEMM input path only)
static __device__ __forceinline__ void split2(float x, ushort& h, ushort& l) {
  h = (ushort)(fbits(x) >> 16);
  const float r = x - bf_f(h);
  l = (ushort)(fbits(r) >> 16);
}
static __device__ __forceinline__ void split8(const float* p, short8v& h, short8v& l) {
  const float4 x0 = *(const float4*)p;
  const float4 x1 = *(const float4*)(p + 4);
  const float xs[8] = {x0.x, x0.y, x0.z, x0.w, x1.x, x1.y, x1.z, x1.w};
  #pragma unroll
  for (int j = 0; j < 8; ++j) {
    ushort hh, ll; split2(xs[j], hh, ll);
    h[j] = (short)hh; l[j] = (short)ll;
  }
}

struct KArgs {
  const float *m, *q, *Ww, *Wb;
  ushort *Hb, *HTb;                     // hat_m bf16 [i][n] and [n][i]
  ushort *Yb[3];                        // y per round, bf16 chain
  ushort *Vb[2];                        // vsum per round, bf16 chain
  ushort *Db[3];                        // dsp per round [b][k*512+i], bf16
  float *summT, *invxT;                 // hat_m row stats (of bf16 values), [k][i]
  float *syT[3], *invyT[3];             // y row stats (of bf16 values), [k][b]
  float *outp;
};

// ===================== K1: GEMM (hi/lo f32-accurate) + bf16 epilogue ============
// 2D XCD partition: region = bid%8 owns a 10(rt) x 4(nt) tile patch.
__global__ __launch_bounds__(256) void k_gemm(KArgs A)
{
  __shared__ float sred[2][2][32];
  const int t = threadIdx.x;
  const int bid = blockIdx.x;
  const int region = bid & 7, idx = bid >> 3;
  const int rt = (region & 1) * 10 + (idx % 10);
  const int nt = (region >> 1) * 4 + (idx / 10);
  const int w = t >> 6, L = t & 63, c = L & 15, g = L >> 4;
  const int wr = w >> 1, wc = w & 1;
  const int r0 = rt * 32, n0 = nt * 64;
  const int arow = r0 + wr * 16 + c;
  const int bcol = n0 + wc * 32 + c;
  const float* asrc = (arow < IC) ? (A.m + (size_t)arow * IDM)
                                  : (A.q + (size_t)(arow - IC) * IDM);
  const float* b0src = A.Ww + (size_t)bcol * IDM;
  const float* b1src = A.Ww + (size_t)(bcol + 16) * IDM;

  f32x4 acc0 = {}, acc1 = {};
  #pragma unroll 2
  for (int kb = 0; kb < IDM; kb += 32) {
    short8v ah, al, bh0, bl0, bh1, bl1;
    split8(asrc + kb + g * 8, ah, al);
    split8(b0src + kb + g * 8, bh0, bl0);
    split8(b1src + kb + g * 8, bh1, bl1);
    acc0 = MFMA(ah, bh0, acc0, 0, 0, 0);
    acc0 = MFMA(ah, bl0, acc0, 0, 0, 0);
    acc0 = MFMA(al, bh0, acc0, 0, 0, 0);
    acc1 = MFMA(ah, bh1, acc1, 0, 0, 0);
    acc1 = MFMA(ah, bl1, acc1, 0, 0, 0);
    acc1 = MFMA(al, bh1, acc1, 0, 0, 0);
  }

  const float bias0 = A.Wb[bcol];
  const float bias1 = A.Wb[bcol + 16];
  ushort h0[4], h1[4];
  float r0s[4], r1s[4];                 // bf16-rounded values (stats source)
  #pragma unroll
  for (int j = 0; j < 4; ++j) {
    h0[j] = bf_rne(acc0[j] + bias0); r0s[j] = bf_f(h0[j]);
    h1[j] = bf_rne(acc1[j] + bias1); r1s[j] = bf_f(h1[j]);
  }

  #pragma unroll
  for (int j = 0; j < 4; ++j) {
    float s = r0s[j] + r1s[j];
    float q2 = r0s[j] * r0s[j] + r1s[j] * r1s[j];
    #pragma unroll
    for (int off = 1; off < 16; off <<= 1) {
      s += __shfl_xor(s, off);
      q2 += __shfl_xor(q2, off);
    }
    if (c == 0) {
      sred[wc][0][wr * 16 + 4 * g + j] = s;
      sred[wc][1][wr * 16 + 4 * g + j] = q2;
    }
  }

  const int rowb = r0 + wr * 16 + 4 * g;
  if (rowb < IC) {
    #pragma unroll
    for (int j = 0; j < 4; ++j) {
      const size_t r = (size_t)(rowb + j) * NOUT;
      A.Hb[r + bcol] = h0[j];
      A.Hb[r + bcol + 16] = h1[j];
    }
    *(ushort4*)&A.HTb[(size_t)bcol * 512 + rowb] = make_ushort4(h0[0], h0[1], h0[2], h0[3]);
    *(ushort4*)&A.HTb[(size_t)(bcol + 16) * 512 + rowb] = make_ushort4(h1[0], h1[1], h1[2], h1[3]);
  } else {
    #pragma unroll
    for (int j = 0; j < 4; ++j) {
      const size_t r = (size_t)(rowb + j - IC) * NOUT;
      A.Yb[0][r + bcol] = h0[j];
      A.Yb[0][r + bcol + 16] = h1[j];
    }
  }
  __syncthreads();
  if (t < 32) {
    const int row = r0 + t;
    const float s = sred[0][0][t] + sred[1][0][t];
    const float q2 = sred[0][1][t] + sred[1][1][t];
    const float inv = rsqrtf(q2 - s * s * (1.0f / 64.0f));
    if (row < IC) {
      A.summT[nt * 512 + row] = s;
      A.invxT[nt * 512 + row] = inv;
    } else {
      A.syT[0][nt * 128 + (row - IC)] = s;
      A.invyT[0][nt * 128 + (row - IC)] = inv;
    }
  }
}

// ===================== K2: corr + softmax (1024 thr, wave = one k) ==============
// Block: (i-tile 16, b-tile 16); grid 256.
// XCD b-ownership: bt = bid&7 -> XCD owns b-slice [bt*16, bt*16+16). Each XCD
// reads all of H once (1 MB, L2-resident across rounds); D/Y/V/stats stay in
// the owning XCD's L2 across produce->consume.
template <int RR>   // 0: round 0 (uniform d, no a-dot); 1: rounds 1,2
__global__ __launch_bounds__(1024) void k_corr(KArgs A)
{
  __shared__ float p_lds[16][256];
  __shared__ float a_lds[16][256];
  const int t = threadIdx.x;
  const int bid = blockIdx.x;
  const int bt = bid & 7, it = bid >> 3;
  const int i0 = it * 16, b0 = bt * 16;
  const int k = t >> 6, L = t & 63, c = L & 15, g = L >> 4;

  const ushort* Yb = A.Yb[RR == 0 ? 0 : (RR == 1 ? 1 : 2)];
  const ushort* Vb = A.Vb[RR == 2 ? 1 : 0];
  const float* syT = A.syT[RR == 0 ? 0 : (RR == 1 ? 1 : 2)];
  const float* invyT = A.invyT[RR == 0 ? 0 : (RR == 1 ? 1 : 2)];
  ushort* Db = A.Db[RR == 0 ? 0 : (RR == 1 ? 1 : 2)];

  const size_t koff = (size_t)k * 64 + g * 8;
  const ushort* pH = A.Hb + (size_t)(i0 + c) * NOUT + koff;
  const ushort* pY = Yb + (size_t)(b0 + c) * NOUT + koff;
  const ushort* pV = Vb + (size_t)(b0 + c) * NOUT + koff;

  f32x4 P = {}, Aa = {};
  #pragma unroll
  for (int ks = 0; ks < 64; ks += 32) {
    const short8v ah = *(const short8v*)(pH + ks);
    const short8v yh = *(const short8v*)(pY + ks);
    P = MFMA(ah, yh, P, 0, 0, 0);
    if (RR) {
      const short8v vh = *(const short8v*)(pV + ks);
      Aa = MFMA(ah, vh, Aa, 0, 0, 0);
    }
  }

  const float syb = syT[k * 128 + b0 + c];
  const float iyb = invyT[k * 128 + b0 + c];
  const f32x4 sm4 = *(const f32x4*)&A.summT[k * 512 + i0 + 4 * g];
  const f32x4 ix4 = *(const f32x4*)&A.invxT[k * 512 + i0 + 4 * g];
  f32x4 pv;
  #pragma unroll
  for (int j = 0; j < 4; ++j)
    pv[j] = tanhf((P[j] - sm4[j] * syb * (1.0f / 64.0f)) * ix4[j] * iyb);
  *(f32x4*)&p_lds[k][c * 16 + 4 * g] = pv;
  if (RR) *(f32x4*)&a_lds[k][c * 16 + 4 * g] = Aa;
  __syncthreads();

  if (t < 256) {
    const int bl = t >> 4, il = t & 15;
    const size_t dbase = (size_t)(b0 + bl) * 8192 + (size_t)(i0 + il);
    if (RR == 0) {
      #pragma unroll
      for (int kk = 0; kk < 16; ++kk)
        Db[dbase + (size_t)kk * 512] = bf_rne(0.0625f - p_lds[kk][t]);
    } else {
      float av[16];
      float mx = -1e30f;
      #pragma unroll
      for (int kk = 0; kk < 16; ++kk) { av[kk] = a_lds[kk][t]; mx = fmaxf(mx, av[kk]); }
      float s = 0.f;
      #pragma unroll
      for (int kk = 0; kk < 16; ++kk) { av[kk] = __expf(av[kk] - mx); s += av[kk]; }
      const float inv = 1.0f / s;
      #pragma unroll
      for (int kk = 0; kk < 16; ++kk)
        Db[dbase + (size_t)kk * 512] = bf_rne(av[kk] * inv - p_lds[kk][t]);
    }
  }
}

// ===================== K3: hat_v MFMA + squash + y/vsum update ==================
// Block: (k, 16 b); grid 128. XCD b-ownership: btile = bid&7 -> same XCD that
// produced this b-slice's D in k_corr and consumes Y/V in the next k_corr.
template <int R>   // 0: vsum=v; 1: vsum+=v; 2: final (outp only)
__global__ __launch_bounds__(256) void k_hatv(KArgs A)
{
  __shared__ float red[3][4][16];
  __shared__ float sscale[16];
  const int t = threadIdx.x;
  const int bid = blockIdx.x;
  const int w = t >> 6, L = t & 63, c = L & 15, g = L >> 4;
  const int k = bid >> 3;
  const int b0 = (bid & 7) * 16;

  const ushort* Db = A.Db[R];
  const ushort* Ybin = (R == 2) ? nullptr : A.Yb[R];
  ushort* Ybout = (R == 2) ? nullptr : A.Yb[R + 1];
  const ushort* Vbin = (R == 1) ? A.Vb[0] : nullptr;
  ushort* Vbout = (R == 2) ? nullptr : A.Vb[R];
  float* syout = (R == 2) ? nullptr : A.syT[R + 1];
  float* invyout = (R == 2) ? nullptr : A.invyT[R + 1];

  const ushort* pA = Db + (size_t)(b0 + c) * 8192 + (size_t)k * 512 + g * 8;
  const ushort* pB = A.HTb + (size_t)(k * 64 + w * 16 + c) * 512 + g * 8;

  f32x4 acc = {};
  #pragma unroll 8
  for (int i = 0; i < 512; i += 32) {
    const short8v ab = *(const short8v*)(pA + i);
    const short8v bb = *(const short8v*)(pB + i);
    acc = MFMA(ab, bb, acc, 0, 0, 0);
  }

  float sq[4];
  #pragma unroll
  for (int j = 0; j < 4; ++j) {
    sq[j] = acc[j] * acc[j];
    #pragma unroll
    for (int off = 1; off < 16; off <<= 1) sq[j] += __shfl_xor(sq[j], off);
  }
  if (c == 0) {
    #pragma unroll
    for (int j = 0; j < 4; ++j) red[0][w][4 * g + j] = sq[j];
  }
  __syncthreads();
  if (t < 16) {
    const float s = red[0][0][t] + red[0][1][t] + red[0][2][t] + red[0][3][t];
    sscale[t] = (s / (1.0f + s)) * rsqrtf(s + 1e-8f);
  }
  __syncthreads();

  const int d = w * 16 + c;
  float s1[4], s2[4];
  #pragma unroll
  for (int j = 0; j < 4; ++j) {
    const int bl_ = 4 * g + j;
    const int b = b0 + bl_;
    const float v = acc[j] * sscale[bl_];
    const size_t idx = (size_t)b * NOUT + (size_t)k * 64 + d;
    if (R == 2) {
      A.outp[idx] = v;
    } else {
      const float vs = (R == 0) ? v : (bf_f(Vbin[idx]) + v);
      Vbout[idx] = bf_rne(vs);
      const float yn = (bf_f(Ybin[idx]) + v) * 0.5f;
      const ushort ynb = bf_rne(yn);
      Ybout[idx] = ynb;
      const float ynr = bf_f(ynb);   // stats of the bf16 y that corr will dot
      s1[j] = ynr; s2[j] = ynr * ynr;
    }
  }
  if (R != 2) {
    #pragma unroll
    for (int j = 0; j < 4; ++j) {
      #pragma unroll
      for (int off = 1; off < 16; off <<= 1) {
        s1[j] += __shfl_xor(s1[j], off);
        s2[j] += __shfl_xor(s2[j], off);
      }
    }
    if (c == 0) {
      #pragma unroll
      for (int j = 0; j < 4; ++j) {
        red[1][w][4 * g + j] = s1[j];
        red[2][w][4 * g + j] = s2[j];
      }
    }
    __syncthreads();
    if (t < 16) {
      const float s = red[1][0][t] + red[1][1][t] + red[1][2][t] + red[1][3][t];
      const float q2 = red[2][0][t] + red[2][1][t] + red[2][2][t] + red[2][3][t];
      syout[k * 128 + b0 + t] = s;
      invyout[k * 128 + b0 + t] = rsqrtf(q2 - s * s * (1.0f / 64.0f));
    }
  }
}

// ===================== launch =====================
extern "C" void kernel_launch(void* const* d_in, const int* in_sizes, int n_in,
                              void* d_out, int out_size, void* d_ws, size_t ws_size,
                              hipStream_t stream) {
  char* w = (char*)d_ws;
  KArgs A;
  A.m  = (const float*)d_in[0];
  A.q  = (const float*)d_in[1];
  A.Ww = (const float*)d_in[2];
  A.Wb = (const float*)d_in[3];
  A.Hb   = (ushort*)(w + 0);          // 1048576
  A.HTb  = (ushort*)(w + 1048576);    // 1048576
  A.Yb[0] = (ushort*)(w + 2097152);   // 262144 each
  A.Yb[1] = (ushort*)(w + 2359296);
  A.Yb[2] = (ushort*)(w + 2621440);
  A.Vb[0] = (ushort*)(w + 2883584);   // 262144 each
  A.Vb[1] = (ushort*)(w + 3145728);
  A.Db[0] = (ushort*)(w + 3407872);   // 2097152 each
  A.Db[1] = (ushort*)(w + 5505024);
  A.Db[2] = (ushort*)(w + 7602176);
  A.summT = (float*)(w + 9699328);    // 32768
  A.invxT = (float*)(w + 9732096);    // 32768
  A.syT[0]   = (float*)(w + 9764864);   // 8192 each
  A.syT[1]   = (float*)(w + 9773056);
  A.syT[2]   = (float*)(w + 9781248);
  A.invyT[0] = (float*)(w + 9789440);
  A.invyT[1] = (float*)(w + 9797632);
  A.invyT[2] = (float*)(w + 9805824);
  A.outp = (float*)d_out;

  k_gemm<<<320, 256, 0, stream>>>(A);
  k_corr<0><<<256, 1024, 0, stream>>>(A);
  k_hatv<0><<<128, 256, 0, stream>>>(A);
  k_corr<1><<<256, 1024, 0, stream>>>(A);
  k_hatv<1><<<128, 256, 0, stream>>>(A);
  k_corr<2><<<256, 1024, 0, stream>>>(A);
  k_hatv<2><<<128, 256, 0, stream>>>(A);
}